// Round 9
// baseline (133.464 us; speedup 1.0000x reference)
//
#include <hip/hip_runtime.h>

typedef unsigned short ushort_t;
typedef __bf16 bf16x8 __attribute__((ext_vector_type(8)));
typedef float f32x4 __attribute__((ext_vector_type(4)));
typedef float f32x16 __attribute__((ext_vector_type(16)));
typedef unsigned short ushortx8 __attribute__((ext_vector_type(8)));
typedef unsigned int uintx4 __attribute__((ext_vector_type(4)));

#define NH 16
#define HS 64
#define CD 1024
#define NB 2
#define NT 2048
#define BT (NB * NT)   // 4096
#define N3 (3 * CD)    // 3072

#define L2E_DIV32 0.04508422002778011f  // log2(e) / 32  (scale = C^-0.5 = 1/32)

// workspace layout (bytes):
// 0        : Xbf 8MB  |  8388608: Wqkv_t 6MB   <- dead after QKV GEMM -> partial region0
// 14680064 : Wo_bf 2MB (live until last GEMM)
// 16777216 : QKV 16MB  [4096][2048] (Q cols 0-1023 prescaled, K cols 1024-2047)
// 33554432 : Vt 8MB    [2048 rows = b*1024+h*64+d][2048 t]
// 41943040 : Obf 8MB
// partial slots: region0 = ws[0 .. 796*18432) ; overflow -> d_out (16MB, dead
// until the final GEMM rewrites it; merge consumes partials before that GEMM).
#define QKV_LD 2048
#define SLOT_BYTES 18432      // 4 waves * (64 lanes * 64B O + 256B m + 256B l)
#define WAVE_BYTES 4608
#define R0_SLOTS 796

// ---------- chunk tables: 51 chunks per bh, ~6 tiles each ----------
// c -> (qb, j, k, t0, t1); slot id = bh*51 + c. qb 0..2 are k=1 (direct write).
__constant__ static const int QB_TAB[51] = {
  0,1,2, 3,3, 4,4, 5,5, 6,6,6, 7,7,7, 8,8,8,
  9,9,9,9, 10,10,10,10, 11,11,11,11,
  12,12,12,12,12, 13,13,13,13,13, 14,14,14,14,14,
  15,15,15,15,15,15};
__constant__ static const int K_TAB[51] = {
  1,1,1, 2,2, 2,2, 2,2, 3,3,3, 3,3,3, 3,3,3,
  4,4,4,4, 4,4,4,4, 4,4,4,4,
  5,5,5,5,5, 5,5,5,5,5, 5,5,5,5,5,
  6,6,6,6,6,6};
__constant__ static const int T0_TAB[51] = {
  0, 0, 0, 0,4, 0,5, 0,6, 0,5,10, 0,6,11, 0,6,12,
  0,5,10,15, 0,6,12,17, 0,6,12,18,
  0,6,11,16,21, 0,6,12,18,23, 0,6,12,18,24,
  0,6,12,17,22,27};
__constant__ static const int T1_TAB[51] = {
  2, 4, 6, 4,8, 5,10, 6,12, 5,10,14, 6,11,16, 6,12,18,
  5,10,15,20, 6,12,17,22, 6,12,18,24,
  6,11,16,21,26, 6,12,18,23,28, 6,12,18,24,30,
  6,12,17,22,27,32};
__constant__ static const int FIRSTC_TAB[16] = {
  0,1,2,3,5,7,9,12,15,18,22,26,30,35,40,45};

// ---------- helpers ----------

__device__ __forceinline__ ushort_t bf16_rne(float f) {
  union { float f; unsigned u; } v; v.f = f;
  unsigned u = v.u;
  unsigned r = (u + 0x7FFFu + ((u >> 16) & 1u)) >> 16;
  return (ushort_t)r;
}

__device__ __forceinline__ float bf2f(ushort_t u) {
  union { unsigned u; float f; } v; v.u = ((unsigned)u) << 16; return v.f;
}

__device__ __forceinline__ void gload_lds16(const ushort_t* g, ushort_t* l) {
  __builtin_amdgcn_global_load_lds(
      (const __attribute__((address_space(1))) unsigned int*)g,
      (__attribute__((address_space(3))) unsigned int*)l, 16, 0, 0);
}

__device__ __forceinline__ f32x4 mfma16(ushortx8 a, ushortx8 b, f32x4 c) {
  return __builtin_amdgcn_mfma_f32_16x16x32_bf16(
      __builtin_bit_cast(bf16x8, a), __builtin_bit_cast(bf16x8, b), c, 0, 0, 0);
}

__device__ __forceinline__ f32x16 mfma32(ushortx8 a, ushortx8 b, f32x16 c) {
  return __builtin_amdgcn_mfma_f32_32x32x16_bf16(
      __builtin_bit_cast(bf16x8, a), __builtin_bit_cast(bf16x8, b), c, 0, 0, 0);
}

__device__ __forceinline__ unsigned cvt_pk_bf16(float lo, float hi) {
  unsigned r;
  asm("v_cvt_pk_bf16_f32 %0, %1, %2" : "=v"(r) : "v"(lo), "v"(hi));
  return r;
}

__device__ __forceinline__ void plswap(unsigned &a, unsigned &b) {
  asm volatile("v_permlane32_swap_b32 %0, %1" : "+v"(a), "+v"(b));
}

__device__ __forceinline__ const char* slot_ptr(const char* wsb, const char* dout, int s) {
  return (s < R0_SLOTS) ? wsb + (size_t)s * SLOT_BYTES
                        : dout + (size_t)(s - R0_SLOTS) * SLOT_BYTES;
}

// ---------- pack kernels ----------

__global__ __launch_bounds__(256)
void pack_cast(const float4* __restrict__ in, ushort_t* __restrict__ out, int n4) {
  const int i = blockIdx.x * 256 + threadIdx.x;
  if (i >= n4) return;
  const float4 v = in[i];
  ushort4 r;
  r.x = bf16_rne(v.x); r.y = bf16_rne(v.y);
  r.z = bf16_rne(v.z); r.w = bf16_rne(v.w);
  *(ushort4*)(out + (size_t)i * 4) = r;
}

// Wq/Wk/Wv: [H][C][HS] fp32 -> Wqkv_t bf16 [3072 rows = s*1024+h*64+d][1024 cols = c]
__global__ __launch_bounds__(256)
void pack_wqkv(const float* __restrict__ Wq, const float* __restrict__ Wk,
               const float* __restrict__ Wv, ushort_t* __restrict__ out) {
  __shared__ ushort_t tile[64 * 66];
  const int sh = blockIdx.y;
  const int s = sh >> 4, h = sh & 15;
  const float* W = (s == 0) ? Wq : ((s == 1) ? Wk : Wv);
  const int c0 = blockIdx.x * 64;
  const int t = threadIdx.x;
#pragma unroll
  for (int j = 0; j < 16; ++j) {
    const int idx = t + j * 256;
    const int ci = idx >> 6, d = idx & 63;
    const float v = W[(size_t)(h * 1024 + c0 + ci) * 64 + d];
    tile[d * 66 + ci] = bf16_rne(v);
  }
  __syncthreads();
#pragma unroll
  for (int j = 0; j < 16; ++j) {
    const int idx = t + j * 256;
    const int d = idx >> 6, ci = idx & 63;
    out[(size_t)(s * 1024 + h * 64 + d) * 1024 + c0 + ci] = tile[d * 66 + ci];
  }
}

// ---------- GEMM: C[m][n] = sum_k A[m][k] * Bt[n][k] ----------
// MODE 0: plain f32 output, ldc = N.
// MODE 1: QKV mode: col<1024 -> bf16*L2E_DIV32 to QKVo (ld 2048);
//         col in [1024,2048) -> bf16 to QKVo; col >= 2048 -> transposed to Vt.

template <int MODE>
__global__ __launch_bounds__(256)
void gemm_bt(const ushort_t* __restrict__ A, const ushort_t* __restrict__ Bt,
             void* __restrict__ Cv, ushort_t* __restrict__ Vt,
             int M, int N, int K) {
  __shared__ __align__(16) ushort_t ldsA[2][128 * 32];
  __shared__ __align__(16) ushort_t ldsB[2][128 * 32];
  const int tid = threadIdx.x;
  const int lane = tid & 63;
  const int wave = tid >> 6;
  const int row0 = blockIdx.y * 128;
  const int col0 = blockIdx.x * 128;
  const int wm = wave >> 1, wn = wave & 1;

  f32x4 acc[4][4] = {};

  const int ce = (tid & 3) * 8;

  auto stage = [&](int buf, int kt) {
    const int kbase = kt * 32;
#pragma unroll
    for (int j = 0; j < 2; ++j) {
      const int r = j * 64 + (tid >> 2);
      gload_lds16(A + (size_t)(row0 + r) * K + kbase + ce,
                  &ldsA[buf][(j * 256 + wave * 64) * 8]);
      gload_lds16(Bt + (size_t)(col0 + r) * K + kbase + ce,
                  &ldsB[buf][(j * 256 + wave * 64) * 8]);
    }
  };

  const int arow_off = (wm * 64 + (lane & 15)) * 32 + (lane >> 4) * 8;
  const int brow_off = (wn * 64 + (lane & 15)) * 32 + (lane >> 4) * 8;

  auto compute = [&](int buf) {
    ushortx8 af[4], bfr[4];
#pragma unroll
    for (int m = 0; m < 4; ++m)
      af[m] = *(const ushortx8*)&ldsA[buf][arow_off + m * 512];
#pragma unroll
    for (int n = 0; n < 4; ++n)
      bfr[n] = *(const ushortx8*)&ldsB[buf][brow_off + n * 512];
#pragma unroll
    for (int m = 0; m < 4; ++m)
#pragma unroll
      for (int n = 0; n < 4; ++n)
        acc[m][n] = mfma16(af[m], bfr[n], acc[m][n]);
  };

  stage(0, 0);
  __syncthreads();
  const int nk = K >> 5;
  for (int kt = 0; kt < nk; ++kt) {
    const int cur = kt & 1;
    if (kt + 1 < nk) stage(cur ^ 1, kt + 1);
    compute(cur);
    __syncthreads();
  }

#pragma unroll
  for (int m = 0; m < 4; ++m) {
    const int rbase = row0 + wm * 64 + m * 16 + (lane >> 4) * 4;
#pragma unroll
    for (int n = 0; n < 4; ++n) {
      const int col = col0 + wn * 64 + n * 16 + (lane & 15);
      if constexpr (MODE == 0) {
#pragma unroll
        for (int i = 0; i < 4; ++i)
          ((float*)Cv)[(size_t)(rbase + i) * N + col] = acc[m][n][i];
      } else {
        if (col < 2048) {
          const float sc = (col < 1024) ? L2E_DIV32 : 1.0f;
#pragma unroll
          for (int i = 0; i < 4; ++i)
            ((ushort_t*)Cv)[(size_t)(rbase + i) * QKV_LD + col] =
                bf16_rne(acc[m][n][i] * sc);
        } else {
          // V: write transposed. Vt row = b*1024 + (col-2048), col = t
          const int dcol = col - 2048;
          const int bI = rbase >> 11;
          const int t0i = rbase & 2047;
          ushort4 pk;
          pk.x = bf16_rne(acc[m][n][0]);
          pk.y = bf16_rne(acc[m][n][1]);
          pk.z = bf16_rne(acc[m][n][2]);
          pk.w = bf16_rne(acc[m][n][3]);
          *(ushort4*)(Vt + (size_t)(bI * 1024 + dcol) * NT + t0i) = pk;
        }
      }
    }
  }
}

// ---------- causal flash attention v8 ----------
// = R7-proven compute/softmax, restructured for occupancy:
//   * uniform ~6-tile key chunks via tables -> 1632 balanced blocks, longest-first
//   * triple-buffered K/V LDS -> ONE s_barrier per tile (write target of
//     stage(t+1) was last read at compute(t-2), ordered by the barrier chain)
//   * partial slots overflow into d_out (dead until final GEMM)

__global__ __launch_bounds__(256, 3)
void attn_fwd8(const ushort_t* __restrict__ QKV, const ushort_t* __restrict__ Vt,
               ushort_t* __restrict__ O, char* __restrict__ wsb,
               char* __restrict__ dout) {
  __shared__ __align__(16) ushort_t KV[3][2][4096];   // [buf][K/V][64 rows x 64]

  const int tid = threadIdx.x;
  const int lane = tid & 63;
  const int w = tid >> 6;
  const int l31 = lane & 31;
  const int h = lane >> 5;

  // block decode via tables; bh in low 5 bits (XCD spread), longest chunks first
  const int x = blockIdx.x;            // 0..1631
  const int bh = x & 31;
  const int c = 50 - (x >> 5);         // 0..50
  const int qb = QB_TAB[c];
  const int k  = K_TAB[c];
  const int t0 = T0_TAB[c];
  const int t1 = T1_TAB[c];
  const int nt = 2 * qb + 2;
  const bool lastc = (t1 == nt);

  const int b = bh >> 4, head = bh & 15;
  const size_t base = (size_t)b * NT * QKV_LD;
  const int qg = qb * 128 + w * 32 + l31;
  const int tmax = lastc ? (2 * qb + (w >> 1)) : (t1 - 1);

  // ---- Q fragments (pre-scaled by log2(e)/32 in QKV GEMM) ----
  ushortx8 qf[4];
  {
    const ushort_t* qp = QKV + base + (size_t)qg * QKV_LD + head * 64 + h * 8;
#pragma unroll
    for (int kc = 0; kc < 4; ++kc) qf[kc] = *(const ushortx8*)(qp + kc * 16);
  }
  asm volatile("s_waitcnt vmcnt(0)" ::: "memory");  // clean vmcnt counting in-loop

  // ---- loop-invariant LDS byte offsets (shared by K-frag and V-frag reads) ----
  int koff[4];
#pragma unroll
  for (int kc = 0; kc < 4; ++kc)
    koff[kc] = l31 * 128 + (((2 * kc + h) ^ (l31 & 7)) * 16);

  // ---- staging source pointers at tile t0 ----
  const int rowA = tid >> 3, ccA = tid & 7;
  const int rowB = 32 + rowA;
  const ushort_t* kg = QKV + base + 1024 + head * 64;
  const ushort_t* vg = Vt + (size_t)(bh * 64) * NT;
  const ushort_t* ksA = kg + (size_t)(t0 * 64 + rowA) * QKV_LD + ((ccA ^ (rowA & 7)) * 8);
  const ushort_t* ksB = kg + (size_t)(t0 * 64 + rowB) * QKV_LD + ((ccA ^ (rowB & 7)) * 8);
  const ushort_t* vsA = vg + (size_t)rowA * NT + t0 * 64 + ((ccA ^ (rowA & 7)) * 8);
  const ushort_t* vsB = vg + (size_t)rowB * NT + t0 * 64 + ((ccA ^ (rowB & 7)) * 8);
  const size_t kadv = (size_t)64 * QKV_LD;

  f32x16 oA = {}, oB = {};
  float m_r = -INFINITY, l_r = 0.f;

  // ---- prologue: stage tile t0 into buffer 0 (4 gload_lds) ----
  gload_lds16(ksA, &KV[0][0][w * 512]);
  gload_lds16(ksB, &KV[0][0][2048 + w * 512]);
  gload_lds16(vsA, &KV[0][1][w * 512]);
  gload_lds16(vsB, &KV[0][1][2048 + w * 512]);

  int cur = 0;
  for (int t = t0; t < t1; ++t) {
    int nxt = cur + 1; if (nxt == 3) nxt = 0;
    if (t + 1 < t1) {
      ksA += kadv; ksB += kadv; vsA += 64; vsB += 64;
      gload_lds16(ksA, &KV[nxt][0][w * 512]);
      gload_lds16(ksB, &KV[nxt][0][2048 + w * 512]);
      gload_lds16(vsA, &KV[nxt][1][w * 512]);
      gload_lds16(vsB, &KV[nxt][1][2048 + w * 512]);
      asm volatile("s_waitcnt vmcnt(4)" ::: "memory");  // tile t landed; t+1 flying
    } else {
      asm volatile("s_waitcnt vmcnt(0)" ::: "memory");
    }
    __builtin_amdgcn_s_barrier();
    asm volatile("" ::: "memory");

    if (t <= tmax) {
      const bool diag = lastc && (t == tmax);
      const bool halfB = diag && ((w & 1) == 0);  // upper 32 keys fully masked
      const char* kb = (const char*)&KV[cur][0][0];
      const char* vb = (const char*)&KV[cur][1][0];

      // --- S^T = K Q^T (log2 units, scale pre-folded) ---
      f32x16 sA = {}, sB = {};
#pragma unroll
      for (int kc = 0; kc < 4; ++kc)
        sA = mfma32(*(const ushortx8*)(kb + koff[kc]), qf[kc], sA);
      if (!halfB) {
#pragma unroll
        for (int kc = 0; kc < 4; ++kc)
          sB = mfma32(*(const ushortx8*)(kb + 4096 + koff[kc]), qf[kc], sB);
      }

      // --- causal mask (diag tiles only) ---
      if (diag) {
#pragma unroll
        for (int r = 0; r < 16; ++r) {
          const int krow = (r & 3) + 8 * (r >> 2) + 4 * h;
          if (halfB) { if (krow > l31) sA[r] = -INFINITY; }
          else       { if (krow > l31) sB[r] = -INFINITY; }
        }
      }

      // --- row max (tree) ---
      float mm[16];
#pragma unroll
      for (int r = 0; r < 16; ++r) mm[r] = halfB ? sA[r] : fmaxf(sA[r], sB[r]);
#pragma unroll
      for (int st = 8; st >= 1; st >>= 1)
#pragma unroll
        for (int r = 0; r < st; ++r) mm[r] = fmaxf(mm[r], mm[r + st]);
      const float mx = fmaxf(mm[0], __shfl_xor(mm[0], 32, 64));

      // --- deferred-max rescale (THR=8 in log2 domain) ---
      if (__any(mx > m_r + 8.0f)) {
        const float mn = fmaxf(m_r, mx);
        const float al = exp2f(m_r - mn);
        m_r = mn; l_r *= al;
#pragma unroll
        for (int r = 0; r < 16; ++r) { oA[r] *= al; oB[r] *= al; }
      }

      // --- exp2 + pack bf16 + partial sums ---
      unsigned u[16];
      float ps[8];
#pragma unroll
      for (int jj = 0; jj < 8; ++jj) {
        const float e0 = exp2f(sA[2 * jj] - m_r);
        const float e1 = exp2f(sA[2 * jj + 1] - m_r);
        u[jj] = cvt_pk_bf16(e0, e1);
        ps[jj] = e0 + e1;
      }
      if (!halfB) {
#pragma unroll
        for (int jj = 0; jj < 8; ++jj) {
          const float e0 = exp2f(sB[2 * jj] - m_r);
          const float e1 = exp2f(sB[2 * jj + 1] - m_r);
          u[8 + jj] = cvt_pk_bf16(e0, e1);
          ps[jj] += e0 + e1;
        }
      }
#pragma unroll
      for (int st = 4; st >= 1; st >>= 1)
#pragma unroll
        for (int r = 0; r < st; ++r) ps[r] += ps[r + st];
      l_r += ps[0] + __shfl_xor(ps[0], 32, 64);

      // --- P^T B-frags via permlane32 swaps ---
      plswap(u[0], u[2]);   plswap(u[1], u[3]);
      plswap(u[4], u[6]);   plswap(u[5], u[7]);
      if (!halfB) {
        plswap(u[8], u[10]);  plswap(u[9], u[11]);
        plswap(u[12], u[14]); plswap(u[13], u[15]);
      }

      // --- O^T += V^T P^T ---
#pragma unroll
      for (int kc = 0; kc < 4; ++kc) {
        if (kc < 2 || !halfB) {
          uintx4 pw;
          pw[0] = u[4 * kc + 0]; pw[1] = u[4 * kc + 1];
          pw[2] = u[4 * kc + 2]; pw[3] = u[4 * kc + 3];
          const ushortx8 pav = __builtin_bit_cast(ushortx8, pw);
          oA = mfma32(*(const ushortx8*)(vb + koff[kc]), pav, oA);
          oB = mfma32(*(const ushortx8*)(vb + 4096 + koff[kc]), pav, oB);
        }
      }
    }

    cur = nxt;
  }

  // ---- epilogue ----
  if (k == 1) {
    const float inv_l = 1.0f / l_r;
    ushort_t* op = O + ((size_t)(b * NT + qg)) * 1024 + head * 64;
#pragma unroll
    for (int db = 0; db < 2; ++db)
#pragma unroll
      for (int g = 0; g < 4; ++g) {
        ushort4 pk;
        pk.x = bf16_rne((db ? oB[4 * g + 0] : oA[4 * g + 0]) * inv_l);
        pk.y = bf16_rne((db ? oB[4 * g + 1] : oA[4 * g + 1]) * inv_l);
        pk.z = bf16_rne((db ? oB[4 * g + 2] : oA[4 * g + 2]) * inv_l);
        pk.w = bf16_rne((db ? oB[4 * g + 3] : oA[4 * g + 3]) * inv_l);
        *(ushort4*)(op + db * 32 + 8 * g + 4 * h) = pk;
      }
  } else {
    const int s = bh * 51 + c;
    char* wb = (char*)slot_ptr(wsb, dout, s) + w * WAVE_BYTES;
#pragma unroll
    for (int g = 0; g < 4; ++g) {
      ushortx8 pk;
#pragma unroll
      for (int e2 = 0; e2 < 8; ++e2)
        pk[e2] = bf16_rne(g < 2 ? oA[g * 8 + e2] : oB[(g - 2) * 8 + e2]);
      *(ushortx8*)(wb + lane * 64 + g * 16) = pk;
    }
    *(float*)(wb + 4096 + lane * 4) = m_r;
    *(float*)(wb + 4352 + lane * 4) = l_r;
  }
}

// ---------- merge partials for qb >= 3 (max-weighted; k up to 6) ----------
__global__ __launch_bounds__(256)
void attn_merge(const char* __restrict__ wsb, const char* __restrict__ dout,
                ushort_t* __restrict__ O) {
  const int x = blockIdx.x;   // 416 = 32 bh * 13 qb
  const int bh = x & 31;
  const int qb = 3 + (x >> 5);
  const int f = FIRSTC_TAB[qb];
  const int k = K_TAB[f];
  const int tid = threadIdx.x;
  const int lane = tid & 63;
  const int w = tid >> 6;
  const int l31 = lane & 31;
  const int h = lane >> 5;
  const int sbase = bh * 51 + f;

  // pass 1: global max over chunks
  float M = -INFINITY;
  for (int jj = 0; jj < k; ++jj) {
    const char* wb = slot_ptr(wsb, dout, sbase + jj) + w * WAVE_BYTES;
    M = fmaxf(M, *(const float*)(wb + 4096 + lane * 4));
  }
  // pass 2: weighted accumulate (slots are L2-hot)
  float o[32];
#pragma unroll
  for (int r = 0; r < 32; ++r) o[r] = 0.f;
  float lacc = 0.f;
  for (int jj = 0; jj < k; ++jj) {
    const char* wb = slot_ptr(wsb, dout, sbase + jj) + w * WAVE_BYTES;
    const float a = exp2f(*(const float*)(wb + 4096 + lane * 4) - M);
    lacc += a * *(const float*)(wb + 4352 + lane * 4);
#pragma unroll
    for (int g = 0; g < 4; ++g) {
      const ushortx8 v = *(const ushortx8*)(wb + lane * 64 + g * 16);
#pragma unroll
      for (int e = 0; e < 8; ++e) o[g * 8 + e] += a * bf2f(v[e]);
    }
  }
  const float inv_l = 1.0f / lacc;
  const int b = bh >> 4, head = bh & 15;
  const int qg = qb * 128 + w * 32 + l31;
  ushort_t* op = O + ((size_t)(b * NT + qg)) * 1024 + head * 64;
#pragma unroll
  for (int db = 0; db < 2; ++db)
#pragma unroll
    for (int g = 0; g < 4; ++g) {
      ushort4 pk;
      pk.x = bf16_rne(o[db * 16 + 4 * g + 0] * inv_l);
      pk.y = bf16_rne(o[db * 16 + 4 * g + 1] * inv_l);
      pk.z = bf16_rne(o[db * 16 + 4 * g + 2] * inv_l);
      pk.w = bf16_rne(o[db * 16 + 4 * g + 3] * inv_l);
      *(ushort4*)(op + db * 32 + 8 * g + 4 * h) = pk;
    }
}

// ---------- launch ----------

extern "C" void kernel_launch(void* const* d_in, const int* in_sizes, int n_in,
                              void* d_out, int out_size, void* d_ws, size_t ws_size,
                              hipStream_t stream) {
  (void)in_sizes; (void)n_in; (void)out_size; (void)ws_size;
  const float* x  = (const float*)d_in[0];
  const float* Wq = (const float*)d_in[1];
  const float* Wk = (const float*)d_in[2];
  const float* Wv = (const float*)d_in[3];
  const float* Wo = (const float*)d_in[4];

  char* ws = (char*)d_ws;
  ushort_t* Xbf    = (ushort_t*)(ws);                        // 4096x1024 bf16 (8 MB)
  ushort_t* Wqkv_t = (ushort_t*)(ws + 8388608);              // 3072x1024 bf16 (6 MB)
  ushort_t* Wo_bf  = (ushort_t*)(ws + 14680064);             // 1024x1024 bf16 (2 MB)
  ushort_t* QKV    = (ushort_t*)(ws + 16777216);             // 4096x2048 bf16 (16 MB)
  ushort_t* Vt     = (ushort_t*)(ws + 33554432);             // 2048x2048 bf16 (8 MB)
  ushort_t* Obf    = (ushort_t*)(ws + 41943040);             // 4096x1024 bf16 (8 MB)

  pack_cast<<<4096, 256, 0, stream>>>((const float4*)x, Xbf, 1048576);
  pack_cast<<<1024, 256, 0, stream>>>((const float4*)Wo, Wo_bf, 262144);
  pack_wqkv<<<dim3(16, 48), 256, 0, stream>>>(Wq, Wk, Wv, Wqkv_t);

  gemm_bt<1><<<dim3(24, 32), 256, 0, stream>>>(Xbf, Wqkv_t, QKV, Vt, BT, N3, CD);
  attn_fwd8<<<1632, 256, 0, stream>>>(QKV, Vt, Obf, ws, (char*)d_out);
  attn_merge<<<416, 256, 0, stream>>>(ws, (char*)d_out, Obf);
  gemm_bt<0><<<dim3(8, 32), 256, 0, stream>>>(Obf, Wo_bf, d_out, nullptr, BT, CD, CD);
}

// Round 10
// 131.047 us; speedup vs baseline: 1.0184x; 1.0184x over previous
//
#include <hip/hip_runtime.h>

typedef unsigned short ushort_t;
typedef __bf16 bf16x8 __attribute__((ext_vector_type(8)));
typedef float f32x4 __attribute__((ext_vector_type(4)));
typedef float f32x16 __attribute__((ext_vector_type(16)));
typedef unsigned short ushortx8 __attribute__((ext_vector_type(8)));
typedef unsigned int uintx4 __attribute__((ext_vector_type(4)));

#define NH 16
#define HS 64
#define CD 1024
#define NB 2
#define NT 2048
#define BT (NB * NT)   // 4096
#define N3 (3 * CD)    // 3072

#define L2E_DIV32 0.04508422002778011f  // log2(e) / 32  (scale = C^-0.5 = 1/32)

// workspace layout (bytes):
// 0        : Xbf 8MB  |  8388608: Wqkv_t 6MB   <- dead after QKV GEMM -> partial region0
// 14680064 : Wo_bf 2MB (live until last GEMM)
// 16777216 : QKV 16MB  [4096][2048] (Q cols 0-1023 prescaled, K cols 1024-2047)
// 33554432 : Vt 8MB    [2048 rows = b*1024+h*64+d][2048 t]
// 41943040 : Obf 8MB
// partial slots: region0 = ws[0 .. 796*18432) ; overflow -> d_out (16MB, dead
// until the final GEMM rewrites it; merge consumes partials before that GEMM).
#define QKV_LD 2048
#define SLOT_BYTES 18432      // 4 waves * (64 lanes * 64B O + 256B m + 256B l)
#define WAVE_BYTES 4608
#define R0_SLOTS 796

// ---------- chunk tables: 51 chunks per bh, ~6 tiles each ----------
__constant__ static const int QB_TAB[51] = {
  0,1,2, 3,3, 4,4, 5,5, 6,6,6, 7,7,7, 8,8,8,
  9,9,9,9, 10,10,10,10, 11,11,11,11,
  12,12,12,12,12, 13,13,13,13,13, 14,14,14,14,14,
  15,15,15,15,15,15};
__constant__ static const int K_TAB[51] = {
  1,1,1, 2,2, 2,2, 2,2, 3,3,3, 3,3,3, 3,3,3,
  4,4,4,4, 4,4,4,4, 4,4,4,4,
  5,5,5,5,5, 5,5,5,5,5, 5,5,5,5,5,
  6,6,6,6,6,6};
__constant__ static const int T0_TAB[51] = {
  0, 0, 0, 0,4, 0,5, 0,6, 0,5,10, 0,6,11, 0,6,12,
  0,5,10,15, 0,6,12,17, 0,6,12,18,
  0,6,11,16,21, 0,6,12,18,23, 0,6,12,18,24,
  0,6,12,17,22,27};
__constant__ static const int T1_TAB[51] = {
  2, 4, 6, 4,8, 5,10, 6,12, 5,10,14, 6,11,16, 6,12,18,
  5,10,15,20, 6,12,17,22, 6,12,18,24,
  6,11,16,21,26, 6,12,18,23,28, 6,12,18,24,30,
  6,12,17,22,27,32};
__constant__ static const int FIRSTC_TAB[16] = {
  0,1,2,3,5,7,9,12,15,18,22,26,30,35,40,45};

// ---------- helpers ----------

__device__ __forceinline__ ushort_t bf16_rne(float f) {
  union { float f; unsigned u; } v; v.f = f;
  unsigned u = v.u;
  unsigned r = (u + 0x7FFFu + ((u >> 16) & 1u)) >> 16;
  return (ushort_t)r;
}

__device__ __forceinline__ float bf2f(ushort_t u) {
  union { unsigned u; float f; } v; v.u = ((unsigned)u) << 16; return v.f;
}

__device__ __forceinline__ void gload_lds16(const ushort_t* g, ushort_t* l) {
  __builtin_amdgcn_global_load_lds(
      (const __attribute__((address_space(1))) unsigned int*)g,
      (__attribute__((address_space(3))) unsigned int*)l, 16, 0, 0);
}

__device__ __forceinline__ f32x4 mfma16(ushortx8 a, ushortx8 b, f32x4 c) {
  return __builtin_amdgcn_mfma_f32_16x16x32_bf16(
      __builtin_bit_cast(bf16x8, a), __builtin_bit_cast(bf16x8, b), c, 0, 0, 0);
}

__device__ __forceinline__ f32x16 mfma32(ushortx8 a, ushortx8 b, f32x16 c) {
  return __builtin_amdgcn_mfma_f32_32x32x16_bf16(
      __builtin_bit_cast(bf16x8, a), __builtin_bit_cast(bf16x8, b), c, 0, 0, 0);
}

__device__ __forceinline__ unsigned cvt_pk_bf16(float lo, float hi) {
  unsigned r;
  asm("v_cvt_pk_bf16_f32 %0, %1, %2" : "=v"(r) : "v"(lo), "v"(hi));
  return r;
}

__device__ __forceinline__ void plswap(unsigned &a, unsigned &b) {
  asm volatile("v_permlane32_swap_b32 %0, %1" : "+v"(a), "+v"(b));
}

__device__ __forceinline__ const char* slot_ptr(const char* wsb, const char* dout, int s) {
  return (s < R0_SLOTS) ? wsb + (size_t)s * SLOT_BYTES
                        : dout + (size_t)(s - R0_SLOTS) * SLOT_BYTES;
}

// ---------- pack kernels ----------

__global__ __launch_bounds__(256)
void pack_cast(const float4* __restrict__ in, ushort_t* __restrict__ out, int n4) {
  const int i = blockIdx.x * 256 + threadIdx.x;
  if (i >= n4) return;
  const float4 v = in[i];
  ushort4 r;
  r.x = bf16_rne(v.x); r.y = bf16_rne(v.y);
  r.z = bf16_rne(v.z); r.w = bf16_rne(v.w);
  *(ushort4*)(out + (size_t)i * 4) = r;
}

// Wq/Wk/Wv: [H][C][HS] fp32 -> Wqkv_t bf16 [3072 rows = s*1024+h*64+d][1024 cols = c]
__global__ __launch_bounds__(256)
void pack_wqkv(const float* __restrict__ Wq, const float* __restrict__ Wk,
               const float* __restrict__ Wv, ushort_t* __restrict__ out) {
  __shared__ ushort_t tile[64 * 66];
  const int sh = blockIdx.y;
  const int s = sh >> 4, h = sh & 15;
  const float* W = (s == 0) ? Wq : ((s == 1) ? Wk : Wv);
  const int c0 = blockIdx.x * 64;
  const int t = threadIdx.x;
#pragma unroll
  for (int j = 0; j < 16; ++j) {
    const int idx = t + j * 256;
    const int ci = idx >> 6, d = idx & 63;
    const float v = W[(size_t)(h * 1024 + c0 + ci) * 64 + d];
    tile[d * 66 + ci] = bf16_rne(v);
  }
  __syncthreads();
#pragma unroll
  for (int j = 0; j < 16; ++j) {
    const int idx = t + j * 256;
    const int d = idx >> 6, ci = idx & 63;
    out[(size_t)(s * 1024 + h * 64 + d) * 1024 + c0 + ci] = tile[d * 66 + ci];
  }
}

// ---------- GEMM: C[m][n] = sum_k A[m][k] * Bt[n][k] ----------
// MODE 0: plain f32 output, ldc = N.
// MODE 1: QKV mode: col<1024 -> bf16*L2E_DIV32 to QKVo (ld 2048);
//         col in [1024,2048) -> bf16 to QKVo; col >= 2048 -> transposed to Vt.

template <int MODE>
__global__ __launch_bounds__(256)
void gemm_bt(const ushort_t* __restrict__ A, const ushort_t* __restrict__ Bt,
             void* __restrict__ Cv, ushort_t* __restrict__ Vt,
             int M, int N, int K) {
  __shared__ __align__(16) ushort_t ldsA[2][128 * 32];
  __shared__ __align__(16) ushort_t ldsB[2][128 * 32];
  const int tid = threadIdx.x;
  const int lane = tid & 63;
  const int wave = tid >> 6;
  const int row0 = blockIdx.y * 128;
  const int col0 = blockIdx.x * 128;
  const int wm = wave >> 1, wn = wave & 1;

  f32x4 acc[4][4] = {};

  const int ce = (tid & 3) * 8;

  auto stage = [&](int buf, int kt) {
    const int kbase = kt * 32;
#pragma unroll
    for (int j = 0; j < 2; ++j) {
      const int r = j * 64 + (tid >> 2);
      gload_lds16(A + (size_t)(row0 + r) * K + kbase + ce,
                  &ldsA[buf][(j * 256 + wave * 64) * 8]);
      gload_lds16(Bt + (size_t)(col0 + r) * K + kbase + ce,
                  &ldsB[buf][(j * 256 + wave * 64) * 8]);
    }
  };

  const int arow_off = (wm * 64 + (lane & 15)) * 32 + (lane >> 4) * 8;
  const int brow_off = (wn * 64 + (lane & 15)) * 32 + (lane >> 4) * 8;

  auto compute = [&](int buf) {
    ushortx8 af[4], bfr[4];
#pragma unroll
    for (int m = 0; m < 4; ++m)
      af[m] = *(const ushortx8*)&ldsA[buf][arow_off + m * 512];
#pragma unroll
    for (int n = 0; n < 4; ++n)
      bfr[n] = *(const ushortx8*)&ldsB[buf][brow_off + n * 512];
#pragma unroll
    for (int m = 0; m < 4; ++m)
#pragma unroll
      for (int n = 0; n < 4; ++n)
        acc[m][n] = mfma16(af[m], bfr[n], acc[m][n]);
  };

  stage(0, 0);
  __syncthreads();
  const int nk = K >> 5;
  for (int kt = 0; kt < nk; ++kt) {
    const int cur = kt & 1;
    if (kt + 1 < nk) stage(cur ^ 1, kt + 1);
    compute(cur);
    __syncthreads();
  }

#pragma unroll
  for (int m = 0; m < 4; ++m) {
    const int rbase = row0 + wm * 64 + m * 16 + (lane >> 4) * 4;
#pragma unroll
    for (int n = 0; n < 4; ++n) {
      const int col = col0 + wn * 64 + n * 16 + (lane & 15);
      if constexpr (MODE == 0) {
#pragma unroll
        for (int i = 0; i < 4; ++i)
          ((float*)Cv)[(size_t)(rbase + i) * N + col] = acc[m][n][i];
      } else {
        if (col < 2048) {
          const float sc = (col < 1024) ? L2E_DIV32 : 1.0f;
#pragma unroll
          for (int i = 0; i < 4; ++i)
            ((ushort_t*)Cv)[(size_t)(rbase + i) * QKV_LD + col] =
                bf16_rne(acc[m][n][i] * sc);
        } else {
          // V: write transposed. Vt row = b*1024 + (col-2048), col = t
          const int dcol = col - 2048;
          const int bI = rbase >> 11;
          const int t0i = rbase & 2047;
          ushort4 pk;
          pk.x = bf16_rne(acc[m][n][0]);
          pk.y = bf16_rne(acc[m][n][1]);
          pk.z = bf16_rne(acc[m][n][2]);
          pk.w = bf16_rne(acc[m][n][3]);
          *(ushort4*)(Vt + (size_t)(bI * 1024 + dcol) * NT + t0i) = pk;
        }
      }
    }
  }
}

// ---------- causal flash attention v9 ----------
// = R8 chunking + R7 double-buffer 2-barrier sync, with SPLIT-HALF softmax
//   (A-half then B-half) to cut peak register liveness -> 4 blocks/CU.

__global__ __launch_bounds__(256, 4)
void attn_fwd9(const ushort_t* __restrict__ QKV, const ushort_t* __restrict__ Vt,
               ushort_t* __restrict__ O, char* __restrict__ wsb,
               char* __restrict__ dout) {
  __shared__ __align__(16) ushort_t KV[2][2][4096];   // [buf][K/V][64 rows x 64]

  const int tid = threadIdx.x;
  const int lane = tid & 63;
  const int w = tid >> 6;
  const int l31 = lane & 31;
  const int h = lane >> 5;

  // block decode via tables; bh in low 5 bits (XCD spread), longest chunks first
  const int x = blockIdx.x;            // 0..1631
  const int bh = x & 31;
  const int c = 50 - (x >> 5);         // 0..50
  const int qb = QB_TAB[c];
  const int k  = K_TAB[c];
  const int t0 = T0_TAB[c];
  const int t1 = T1_TAB[c];
  const int nt = 2 * qb + 2;
  const bool lastc = (t1 == nt);

  const int b = bh >> 4, head = bh & 15;
  const size_t base = (size_t)b * NT * QKV_LD;
  const int qg = qb * 128 + w * 32 + l31;
  const int tmax = lastc ? (2 * qb + (w >> 1)) : (t1 - 1);

  // ---- loop-invariant LDS byte offsets (shared by K-frag and V-frag reads) ----
  int koff[4];
#pragma unroll
  for (int kc = 0; kc < 4; ++kc)
    koff[kc] = l31 * 128 + (((2 * kc + h) ^ (l31 & 7)) * 16);

  // ---- staging source pointers at tile t0 ----
  const int rowA = tid >> 3, ccA = tid & 7;
  const int rowB = 32 + rowA;
  const ushort_t* kg = QKV + base + 1024 + head * 64;
  const ushort_t* vg = Vt + (size_t)(bh * 64) * NT;
  const ushort_t* ksA = kg + (size_t)(t0 * 64 + rowA) * QKV_LD + ((ccA ^ (rowA & 7)) * 8);
  const ushort_t* ksB = kg + (size_t)(t0 * 64 + rowB) * QKV_LD + ((ccA ^ (rowB & 7)) * 8);
  const ushort_t* vsA = vg + (size_t)rowA * NT + t0 * 64 + ((ccA ^ (rowA & 7)) * 8);
  const ushort_t* vsB = vg + (size_t)rowB * NT + t0 * 64 + ((ccA ^ (rowB & 7)) * 8);
  const size_t kadv = (size_t)64 * QKV_LD;

  // ---- prologue: stage tile t0 into buffer 0 FIRST, then Q loads ----
  // (uniform in-loop vmcnt(4) then covers Q on the first iteration: oldest
  //  outstanding = stage(t0) 4 + Q 4 + stage(t0+1) 4 -> wait to 4 lands t0+Q)
  gload_lds16(ksA, &KV[0][0][w * 512]);
  gload_lds16(ksB, &KV[0][0][2048 + w * 512]);
  gload_lds16(vsA, &KV[0][1][w * 512]);
  gload_lds16(vsB, &KV[0][1][2048 + w * 512]);

  ushortx8 qf[4];
  {
    const ushort_t* qp = QKV + base + (size_t)qg * QKV_LD + head * 64 + h * 8;
#pragma unroll
    for (int kc = 0; kc < 4; ++kc) qf[kc] = *(const ushortx8*)(qp + kc * 16);
  }

  f32x16 oA = {}, oB = {};
  float m_r = -INFINITY, l_r = 0.f;

  // one 32-key half: mask -> max -> defer-rescale -> exp2/pack -> PV(kc0,kc0+1)
  auto half_pass = [&](f32x16 s, const char* vb, const int kc0, const bool msk) {
    if (msk) {
#pragma unroll
      for (int r = 0; r < 16; ++r) {
        const int krow = (r & 3) + 8 * (r >> 2) + 4 * h;
        if (krow > l31) s[r] = -INFINITY;
      }
    }
    float mm[8];
#pragma unroll
    for (int r = 0; r < 8; ++r) mm[r] = fmaxf(s[r], s[r + 8]);
#pragma unroll
    for (int st = 4; st >= 1; st >>= 1)
#pragma unroll
      for (int r = 0; r < st; ++r) mm[r] = fmaxf(mm[r], mm[r + st]);
    const float mx = fmaxf(mm[0], __shfl_xor(mm[0], 32, 64));
    if (__any(mx > m_r + 8.0f)) {
      const float mn = fmaxf(m_r, mx);
      const float al = exp2f(m_r - mn);
      m_r = mn; l_r *= al;
#pragma unroll
      for (int r = 0; r < 16; ++r) { oA[r] *= al; oB[r] *= al; }
    }
    unsigned u[8];
    float ps[4];
#pragma unroll
    for (int jj = 0; jj < 4; ++jj) ps[jj] = 0.f;
#pragma unroll
    for (int jj = 0; jj < 8; ++jj) {
      const float e0 = exp2f(s[2 * jj] - m_r);
      const float e1 = exp2f(s[2 * jj + 1] - m_r);
      u[jj] = cvt_pk_bf16(e0, e1);
      ps[jj & 3] += e0 + e1;
    }
    ps[0] += ps[2]; ps[1] += ps[3]; ps[0] += ps[1];
    l_r += ps[0] + __shfl_xor(ps[0], 32, 64);
    plswap(u[0], u[2]); plswap(u[1], u[3]);
    plswap(u[4], u[6]); plswap(u[5], u[7]);
#pragma unroll
    for (int q2 = 0; q2 < 2; ++q2) {
      uintx4 pw;
      pw[0] = u[4 * q2 + 0]; pw[1] = u[4 * q2 + 1];
      pw[2] = u[4 * q2 + 2]; pw[3] = u[4 * q2 + 3];
      const ushortx8 pav = __builtin_bit_cast(ushortx8, pw);
      oA = mfma32(*(const ushortx8*)(vb + koff[kc0 + q2]), pav, oA);
      oB = mfma32(*(const ushortx8*)(vb + 4096 + koff[kc0 + q2]), pav, oB);
    }
  };

  int curb = 0;
  for (int t = t0; t < t1; ++t) {
    const int nxt = curb ^ 1;
    if (t + 1 < t1) {
      ksA += kadv; ksB += kadv; vsA += 64; vsB += 64;
      gload_lds16(ksA, &KV[nxt][0][w * 512]);
      gload_lds16(ksB, &KV[nxt][0][2048 + w * 512]);
      gload_lds16(vsA, &KV[nxt][1][w * 512]);
      gload_lds16(vsB, &KV[nxt][1][2048 + w * 512]);
      asm volatile("s_waitcnt vmcnt(4)" ::: "memory");  // tile t (+Q) landed
    } else {
      asm volatile("s_waitcnt vmcnt(0)" ::: "memory");
    }
    __builtin_amdgcn_s_barrier();
    asm volatile("" ::: "memory");

    if (t <= tmax) {
      const bool diag = lastc && (t == tmax);
      const bool halfB = diag && ((w & 1) == 0);  // upper 32 keys fully masked
      const char* kb = (const char*)&KV[curb][0][0];
      const char* vb = (const char*)&KV[curb][1][0];

      // --- A-half: keys key0..key0+31 ---
      {
        f32x16 sA = {};
#pragma unroll
        for (int kc = 0; kc < 4; ++kc)
          sA = mfma32(*(const ushortx8*)(kb + koff[kc]), qf[kc], sA);
        half_pass(sA, vb, 0, diag && halfB);
      }
      // --- B-half: keys key0+32..key0+63 (skipped when fully masked) ---
      if (!halfB) {
        f32x16 sB = {};
#pragma unroll
        for (int kc = 0; kc < 4; ++kc)
          sB = mfma32(*(const ushortx8*)(kb + 4096 + koff[kc]), qf[kc], sB);
        half_pass(sB, vb, 2, diag);
      }
    }

    __builtin_amdgcn_s_barrier();   // all reads of buf curb done before overwrite
    asm volatile("" ::: "memory");
    curb ^= 1;
  }

  // ---- epilogue ----
  if (k == 1) {
    const float inv_l = 1.0f / l_r;
    ushort_t* op = O + ((size_t)(b * NT + qg)) * 1024 + head * 64;
#pragma unroll
    for (int db = 0; db < 2; ++db)
#pragma unroll
      for (int g = 0; g < 4; ++g) {
        ushort4 pk;
        pk.x = bf16_rne((db ? oB[4 * g + 0] : oA[4 * g + 0]) * inv_l);
        pk.y = bf16_rne((db ? oB[4 * g + 1] : oA[4 * g + 1]) * inv_l);
        pk.z = bf16_rne((db ? oB[4 * g + 2] : oA[4 * g + 2]) * inv_l);
        pk.w = bf16_rne((db ? oB[4 * g + 3] : oA[4 * g + 3]) * inv_l);
        *(ushort4*)(op + db * 32 + 8 * g + 4 * h) = pk;
      }
  } else {
    const int s = bh * 51 + c;
    char* wb = (char*)slot_ptr(wsb, dout, s) + w * WAVE_BYTES;
#pragma unroll
    for (int g = 0; g < 4; ++g) {
      ushortx8 pk;
#pragma unroll
      for (int e2 = 0; e2 < 8; ++e2)
        pk[e2] = bf16_rne(g < 2 ? oA[g * 8 + e2] : oB[(g - 2) * 8 + e2]);
      *(ushortx8*)(wb + lane * 64 + g * 16) = pk;
    }
    *(float*)(wb + 4096 + lane * 4) = m_r;
    *(float*)(wb + 4352 + lane * 4) = l_r;
  }
}

// ---------- merge partials for qb >= 3 (max-weighted; k up to 6) ----------
__global__ __launch_bounds__(256)
void attn_merge(const char* __restrict__ wsb, const char* __restrict__ dout,
                ushort_t* __restrict__ O) {
  const int x = blockIdx.x;   // 416 = 32 bh * 13 qb
  const int bh = x & 31;
  const int qb = 3 + (x >> 5);
  const int f = FIRSTC_TAB[qb];
  const int k = K_TAB[f];
  const int tid = threadIdx.x;
  const int lane = tid & 63;
  const int w = tid >> 6;
  const int l31 = lane & 31;
  const int h = lane >> 5;
  const int sbase = bh * 51 + f;

  // pass 1: global max over chunks
  float M = -INFINITY;
  for (int jj = 0; jj < k; ++jj) {
    const char* wb = slot_ptr(wsb, dout, sbase + jj) + w * WAVE_BYTES;
    M = fmaxf(M, *(const float*)(wb + 4096 + lane * 4));
  }
  // pass 2: weighted accumulate (slots are L2-hot)
  float o[32];
#pragma unroll
  for (int r = 0; r < 32; ++r) o[r] = 0.f;
  float lacc = 0.f;
  for (int jj = 0; jj < k; ++jj) {
    const char* wb = slot_ptr(wsb, dout, sbase + jj) + w * WAVE_BYTES;
    const float a = exp2f(*(const float*)(wb + 4096 + lane * 4) - M);
    lacc += a * *(const float*)(wb + 4352 + lane * 4);
#pragma unroll
    for (int g = 0; g < 4; ++g) {
      const ushortx8 v = *(const ushortx8*)(wb + lane * 64 + g * 16);
#pragma unroll
      for (int e = 0; e < 8; ++e) o[g * 8 + e] += a * bf2f(v[e]);
    }
  }
  const float inv_l = 1.0f / lacc;
  const int b = bh >> 4, head = bh & 15;
  const int qg = qb * 128 + w * 32 + l31;
  ushort_t* op = O + ((size_t)(b * NT + qg)) * 1024 + head * 64;
#pragma unroll
  for (int db = 0; db < 2; ++db)
#pragma unroll
    for (int g = 0; g < 4; ++g) {
      ushort4 pk;
      pk.x = bf16_rne(o[db * 16 + 4 * g + 0] * inv_l);
      pk.y = bf16_rne(o[db * 16 + 4 * g + 1] * inv_l);
      pk.z = bf16_rne(o[db * 16 + 4 * g + 2] * inv_l);
      pk.w = bf16_rne(o[db * 16 + 4 * g + 3] * inv_l);
      *(ushort4*)(op + db * 32 + 8 * g + 4 * h) = pk;
    }
}

// ---------- launch ----------

extern "C" void kernel_launch(void* const* d_in, const int* in_sizes, int n_in,
                              void* d_out, int out_size, void* d_ws, size_t ws_size,
                              hipStream_t stream) {
  (void)in_sizes; (void)n_in; (void)out_size; (void)ws_size;
  const float* x  = (const float*)d_in[0];
  const float* Wq = (const float*)d_in[1];
  const float* Wk = (const float*)d_in[2];
  const float* Wv = (const float*)d_in[3];
  const float* Wo = (const float*)d_in[4];

  char* ws = (char*)d_ws;
  ushort_t* Xbf    = (ushort_t*)(ws);                        // 4096x1024 bf16 (8 MB)
  ushort_t* Wqkv_t = (ushort_t*)(ws + 8388608);              // 3072x1024 bf16 (6 MB)
  ushort_t* Wo_bf  = (ushort_t*)(ws + 14680064);             // 1024x1024 bf16 (2 MB)
  ushort_t* QKV    = (ushort_t*)(ws + 16777216);             // 4096x2048 bf16 (16 MB)
  ushort_t* Vt     = (ushort_t*)(ws + 33554432);             // 2048x2048 bf16 (8 MB)
  ushort_t* Obf    = (ushort_t*)(ws + 41943040);             // 4096x1024 bf16 (8 MB)

  pack_cast<<<4096, 256, 0, stream>>>((const float4*)x, Xbf, 1048576);
  pack_cast<<<1024, 256, 0, stream>>>((const float4*)Wo, Wo_bf, 262144);
  pack_wqkv<<<dim3(16, 48), 256, 0, stream>>>(Wq, Wk, Wv, Wqkv_t);

  gemm_bt<1><<<dim3(24, 32), 256, 0, stream>>>(Xbf, Wqkv_t, QKV, Vt, BT, N3, CD);
  attn_fwd9<<<1632, 256, 0, stream>>>(QKV, Vt, Obf, ws, (char*)d_out);
  attn_merge<<<416, 256, 0, stream>>>(ws, (char*)d_out, Obf);
  gemm_bt<0><<<dim3(8, 32), 256, 0, stream>>>(Obf, Wo_bf, d_out, nullptr, BT, CD, CD);
}

// Round 14
// 122.794 us; speedup vs baseline: 1.0869x; 1.0672x over previous
//
#include <hip/hip_runtime.h>

typedef unsigned short ushort_t;
typedef __bf16 bf16x8 __attribute__((ext_vector_type(8)));
typedef float f32x4 __attribute__((ext_vector_type(4)));
typedef float f32x16 __attribute__((ext_vector_type(16)));
typedef unsigned short ushortx8 __attribute__((ext_vector_type(8)));
typedef unsigned int uintx4 __attribute__((ext_vector_type(4)));

#define NH 16
#define HS 64
#define CD 1024
#define NB 2
#define NT 2048
#define BT (NB * NT)   // 4096
#define N3 (3 * CD)    // 3072

#define L2E_DIV32 0.04508422002778011f  // log2(e) / 32  (scale = C^-0.5 = 1/32)

// workspace layout (bytes):
// 0        : Xbf 8MB  |  8388608: Wqkv_t 6MB   <- dead after QKV GEMM -> partial region0
// 14680064 : Wo_bf 2MB (live until last GEMM)
// 16777216 : QKV 16MB  [4096][2048] (Q cols 0-1023 prescaled, K cols 1024-2047)
// 33554432 : Vt 8MB    [2048 rows = b*1024+h*64+d][2048 t]
// 41943040 : Obf 8MB
// partial slots: region0 = ws[0 .. 796*18432 = 14671872) ; overflow -> d_out
// (16MB, dead until the final GEMM rewrites it; merge consumes partials first).
#define QKV_LD 2048
#define SLOT_BYTES 18432      // 4 waves * (64 lanes * 64B O + 256B m + 256B l)
#define WAVE_BYTES 4608
#define R0_SLOTS 796

// ---------- chunk tables: 32 chunks per bh (EXACTLY one round of 1024 blocks),
// ~8.5 tiles each, LPT order (c=0 longest). slot id = bh*32 + c. ----------
__constant__ static const int QB_TAB[32] = {
  10,10,15,15, 4, 9, 9,13,14,14,14,15, 8, 8,12,12,
  13,13, 3, 7, 7,11,11,11,12, 6, 6, 2, 5, 5, 1, 0};
__constant__ static const int T0_TAB[32] = {
   0,11, 0,11, 0, 0,10, 0, 0,10,20,22, 0, 9, 0, 9,
  10,19, 0, 0, 8, 0, 8,16,18, 0, 7, 0, 0, 6, 0, 0};
__constant__ static const int T1_TAB[32] = {
  11,22,11,22,10,10,20,10,10,20,30,32, 9,18, 9,18,
  19,28, 8, 8,16, 8,16,24,26, 7,14, 6, 6,12, 4, 2};
__constant__ static const int K_TAB[32] = {
   2, 2, 3, 3, 1, 2, 2, 3, 3, 3, 3, 3, 2, 2, 3, 3,
   3, 3, 1, 2, 2, 3, 3, 3, 3, 2, 2, 1, 2, 2, 1, 1};
// merge: qb 5..15 (qi 0..10) -> chunk ids c of that qb
__constant__ static const int MC_TAB[11][3] = {
  {28,29, 0}, {25,26, 0}, {19,20, 0}, {12,13, 0}, { 5, 6, 0}, { 0, 1, 0},
  {21,22,23}, {14,15,24}, { 7,16,17}, { 8, 9,10}, { 2, 3,11}};

// ---------- helpers ----------

__device__ __forceinline__ ushort_t bf16_rne(float f) {
  union { float f; unsigned u; } v; v.f = f;
  unsigned u = v.u;
  unsigned r = (u + 0x7FFFu + ((u >> 16) & 1u)) >> 16;
  return (ushort_t)r;
}

__device__ __forceinline__ float bf2f(ushort_t u) {
  union { unsigned u; float f; } v; v.u = ((unsigned)u) << 16; return v.f;
}

__device__ __forceinline__ void gload_lds16(const ushort_t* g, ushort_t* l) {
  __builtin_amdgcn_global_load_lds(
      (const __attribute__((address_space(1))) unsigned int*)g,
      (__attribute__((address_space(3))) unsigned int*)l, 16, 0, 0);
}

__device__ __forceinline__ f32x4 mfma16(ushortx8 a, ushortx8 b, f32x4 c) {
  return __builtin_amdgcn_mfma_f32_16x16x32_bf16(
      __builtin_bit_cast(bf16x8, a), __builtin_bit_cast(bf16x8, b), c, 0, 0, 0);
}

__device__ __forceinline__ f32x16 mfma32(ushortx8 a, ushortx8 b, f32x16 c) {
  return __builtin_amdgcn_mfma_f32_32x32x16_bf16(
      __builtin_bit_cast(bf16x8, a), __builtin_bit_cast(bf16x8, b), c, 0, 0, 0);
}

__device__ __forceinline__ unsigned cvt_pk_bf16(float lo, float hi) {
  unsigned r;
  asm("v_cvt_pk_bf16_f32 %0, %1, %2" : "=v"(r) : "v"(lo), "v"(hi));
  return r;
}

__device__ __forceinline__ void plswap(unsigned &a, unsigned &b) {
  asm volatile("v_permlane32_swap_b32 %0, %1" : "+v"(a), "+v"(b));
}

__device__ __forceinline__ const char* slot_ptr(const char* wsb, const char* dout, int s) {
  return (s < R0_SLOTS) ? wsb + (size_t)s * SLOT_BYTES
                        : dout + (size_t)(s - R0_SLOTS) * SLOT_BYTES;
}

// ---------- pack kernels ----------

// fused: blocks 0..4095 convert x (1M float4), 4096..5119 convert Wo (256K float4)
__global__ __launch_bounds__(256)
void pack_cast2(const float4* __restrict__ x, ushort_t* __restrict__ xout,
                const float4* __restrict__ wo, ushort_t* __restrict__ woout) {
  const int bid = blockIdx.x;
  const float4* in = (bid < 4096) ? x : wo;
  ushort_t* out = (bid < 4096) ? xout : woout;
  const int i = ((bid < 4096) ? bid : (bid - 4096)) * 256 + threadIdx.x;
  const float4 v = in[i];
  ushort4 r;
  r.x = bf16_rne(v.x); r.y = bf16_rne(v.y);
  r.z = bf16_rne(v.z); r.w = bf16_rne(v.w);
  *(ushort4*)(out + (size_t)i * 4) = r;
}

// Wq/Wk/Wv: [H][C][HS] fp32 -> Wqkv_t bf16 [3072 rows = s*1024+h*64+d][1024 cols = c]
__global__ __launch_bounds__(256)
void pack_wqkv(const float* __restrict__ Wq, const float* __restrict__ Wk,
               const float* __restrict__ Wv, ushort_t* __restrict__ out) {
  __shared__ ushort_t tile[64 * 66];
  const int sh = blockIdx.y;
  const int s = sh >> 4, h = sh & 15;
  const float* W = (s == 0) ? Wq : ((s == 1) ? Wk : Wv);
  const int c0 = blockIdx.x * 64;
  const int t = threadIdx.x;
#pragma unroll
  for (int j = 0; j < 16; ++j) {
    const int idx = t + j * 256;
    const int ci = idx >> 6, d = idx & 63;
    const float v = W[(size_t)(h * 1024 + c0 + ci) * 64 + d];
    tile[d * 66 + ci] = bf16_rne(v);
  }
  __syncthreads();
#pragma unroll
  for (int j = 0; j < 16; ++j) {
    const int idx = t + j * 256;
    const int d = idx >> 6, ci = idx & 63;
    out[(size_t)(s * 1024 + h * 64 + d) * 1024 + c0 + ci] = tile[d * 66 + ci];
  }
}

// ---------- GEMM: C[m][n] = sum_k A[m][k] * Bt[n][k] ----------
// MODE 0: plain f32 output, ldc = N.
// MODE 1: QKV mode: col<1024 -> bf16*L2E_DIV32 to QKVo (ld 2048);
//         col in [1024,2048) -> bf16 to QKVo; col >= 2048 -> transposed to Vt.

template <int MODE>
__global__ __launch_bounds__(256)
void gemm_bt(const ushort_t* __restrict__ A, const ushort_t* __restrict__ Bt,
             void* __restrict__ Cv, ushort_t* __restrict__ Vt,
             int M, int N, int K) {
  __shared__ __align__(16) ushort_t ldsA[2][128 * 32];
  __shared__ __align__(16) ushort_t ldsB[2][128 * 32];
  const int tid = threadIdx.x;
  const int lane = tid & 63;
  const int wave = tid >> 6;
  const int row0 = blockIdx.y * 128;
  const int col0 = blockIdx.x * 128;
  const int wm = wave >> 1, wn = wave & 1;

  f32x4 acc[4][4] = {};

  const int ce = (tid & 3) * 8;

  auto stage = [&](int buf, int kt) {
    const int kbase = kt * 32;
#pragma unroll
    for (int j = 0; j < 2; ++j) {
      const int r = j * 64 + (tid >> 2);
      gload_lds16(A + (size_t)(row0 + r) * K + kbase + ce,
                  &ldsA[buf][(j * 256 + wave * 64) * 8]);
      gload_lds16(Bt + (size_t)(col0 + r) * K + kbase + ce,
                  &ldsB[buf][(j * 256 + wave * 64) * 8]);
    }
  };

  const int arow_off = (wm * 64 + (lane & 15)) * 32 + (lane >> 4) * 8;
  const int brow_off = (wn * 64 + (lane & 15)) * 32 + (lane >> 4) * 8;

  auto compute = [&](int buf) {
    ushortx8 af[4], bfr[4];
#pragma unroll
    for (int m = 0; m < 4; ++m)
      af[m] = *(const ushortx8*)&ldsA[buf][arow_off + m * 512];
#pragma unroll
    for (int n = 0; n < 4; ++n)
      bfr[n] = *(const ushortx8*)&ldsB[buf][brow_off + n * 512];
#pragma unroll
    for (int m = 0; m < 4; ++m)
#pragma unroll
      for (int n = 0; n < 4; ++n)
        acc[m][n] = mfma16(af[m], bfr[n], acc[m][n]);
  };

  stage(0, 0);
  __syncthreads();
  const int nk = K >> 5;
  for (int kt = 0; kt < nk; ++kt) {
    const int cur = kt & 1;
    if (kt + 1 < nk) stage(cur ^ 1, kt + 1);
    compute(cur);
    __syncthreads();
  }

#pragma unroll
  for (int m = 0; m < 4; ++m) {
    const int rbase = row0 + wm * 64 + m * 16 + (lane >> 4) * 4;
#pragma unroll
    for (int n = 0; n < 4; ++n) {
      const int col = col0 + wn * 64 + n * 16 + (lane & 15);
      if constexpr (MODE == 0) {
#pragma unroll
        for (int i = 0; i < 4; ++i)
          ((float*)Cv)[(size_t)(rbase + i) * N + col] = acc[m][n][i];
      } else {
        if (col < 2048) {
          const float sc = (col < 1024) ? L2E_DIV32 : 1.0f;
#pragma unroll
          for (int i = 0; i < 4; ++i)
            ((ushort_t*)Cv)[(size_t)(rbase + i) * QKV_LD + col] =
                bf16_rne(acc[m][n][i] * sc);
        } else {
          // V: write transposed. Vt row = b*1024 + (col-2048), col = t
          const int dcol = col - 2048;
          const int bI = rbase >> 11;
          const int t0i = rbase & 2047;
          ushort4 pk;
          pk.x = bf16_rne(acc[m][n][0]);
          pk.y = bf16_rne(acc[m][n][1]);
          pk.z = bf16_rne(acc[m][n][2]);
          pk.w = bf16_rne(acc[m][n][3]);
          *(ushort4*)(Vt + (size_t)(bI * 1024 + dcol) * NT + t0i) = pk;
        }
      }
    }
  }
}

// ---------- causal flash attention v11 ----------
// = R9 kernel body verbatim (split-half softmax, 2-buffer / 2-barrier, counted
//   vmcnt), with EXACTLY-ONE-ROUND chunking: 32 chunks/bh -> 1024 blocks
//   (= 4/CU capacity), ~8.5 tiles each, LPT order. NO persistence, NO atomics.

__global__ __launch_bounds__(256, 4)
void attn_fwd11(const ushort_t* __restrict__ QKV, const ushort_t* __restrict__ Vt,
                ushort_t* __restrict__ O, char* __restrict__ wsb,
                char* __restrict__ dout) {
  __shared__ __align__(16) ushort_t KV[2][2][4096];   // [buf][K/V][64 rows x 64]

  const int tid = threadIdx.x;
  const int lane = tid & 63;
  const int w = tid >> 6;
  const int l31 = lane & 31;
  const int h = lane >> 5;

  // block decode via tables; bh in low 5 bits (XCD spread), longest chunks first
  const int x = blockIdx.x;            // 0..1023
  const int bh = x & 31;
  const int c = x >> 5;                // 0..31, c=0 longest (LPT)
  const int qb = QB_TAB[c];
  const int k  = K_TAB[c];
  const int t0 = T0_TAB[c];
  const int t1 = T1_TAB[c];
  const int nt = 2 * qb + 2;
  const bool lastc = (t1 == nt);

  const int b = bh >> 4, head = bh & 15;
  const size_t base = (size_t)b * NT * QKV_LD;
  const int qg = qb * 128 + w * 32 + l31;
  const int tmax = lastc ? (2 * qb + (w >> 1)) : (t1 - 1);

  // ---- loop-invariant LDS byte offsets (shared by K-frag and V-frag reads) ----
  int koff[4];
#pragma unroll
  for (int kc = 0; kc < 4; ++kc)
    koff[kc] = l31 * 128 + (((2 * kc + h) ^ (l31 & 7)) * 16);

  // ---- staging source pointers at tile t0 ----
  const int rowA = tid >> 3, ccA = tid & 7;
  const int rowB = 32 + rowA;
  const ushort_t* kg = QKV + base + 1024 + head * 64;
  const ushort_t* vg = Vt + (size_t)(bh * 64) * NT;
  const ushort_t* ksA = kg + (size_t)(t0 * 64 + rowA) * QKV_LD + ((ccA ^ (rowA & 7)) * 8);
  const ushort_t* ksB = kg + (size_t)(t0 * 64 + rowB) * QKV_LD + ((ccA ^ (rowB & 7)) * 8);
  const ushort_t* vsA = vg + (size_t)rowA * NT + t0 * 64 + ((ccA ^ (rowA & 7)) * 8);
  const ushort_t* vsB = vg + (size_t)rowB * NT + t0 * 64 + ((ccA ^ (rowB & 7)) * 8);
  const size_t kadv = (size_t)64 * QKV_LD;

  // ---- prologue: stage tile t0 into buffer 0 FIRST, then Q loads ----
  gload_lds16(ksA, &KV[0][0][w * 512]);
  gload_lds16(ksB, &KV[0][0][2048 + w * 512]);
  gload_lds16(vsA, &KV[0][1][w * 512]);
  gload_lds16(vsB, &KV[0][1][2048 + w * 512]);

  ushortx8 qf[4];
  {
    const ushort_t* qp = QKV + base + (size_t)qg * QKV_LD + head * 64 + h * 8;
#pragma unroll
    for (int kc = 0; kc < 4; ++kc) qf[kc] = *(const ushortx8*)(qp + kc * 16);
  }

  f32x16 oA = {}, oB = {};
  float m_r = -INFINITY, l_r = 0.f;

  // one 32-key half: mask -> max -> defer-rescale -> exp2/pack -> PV(kc0,kc0+1)
  auto half_pass = [&](f32x16 s, const char* vb, const int kc0, const bool msk) {
    if (msk) {
#pragma unroll
      for (int r = 0; r < 16; ++r) {
        const int krow = (r & 3) + 8 * (r >> 2) + 4 * h;
        if (krow > l31) s[r] = -INFINITY;
      }
    }
    float mm[8];
#pragma unroll
    for (int r = 0; r < 8; ++r) mm[r] = fmaxf(s[r], s[r + 8]);
#pragma unroll
    for (int st = 4; st >= 1; st >>= 1)
#pragma unroll
      for (int r = 0; r < st; ++r) mm[r] = fmaxf(mm[r], mm[r + st]);
    const float mx = fmaxf(mm[0], __shfl_xor(mm[0], 32, 64));
    if (__any(mx > m_r + 8.0f)) {
      const float mn = fmaxf(m_r, mx);
      const float al = exp2f(m_r - mn);
      m_r = mn; l_r *= al;
#pragma unroll
      for (int r = 0; r < 16; ++r) { oA[r] *= al; oB[r] *= al; }
    }
    unsigned u[8];
    float ps[4];
#pragma unroll
    for (int jj = 0; jj < 4; ++jj) ps[jj] = 0.f;
#pragma unroll
    for (int jj = 0; jj < 8; ++jj) {
      const float e0 = exp2f(s[2 * jj] - m_r);
      const float e1 = exp2f(s[2 * jj + 1] - m_r);
      u[jj] = cvt_pk_bf16(e0, e1);
      ps[jj & 3] += e0 + e1;
    }
    ps[0] += ps[2]; ps[1] += ps[3]; ps[0] += ps[1];
    l_r += ps[0] + __shfl_xor(ps[0], 32, 64);
    plswap(u[0], u[2]); plswap(u[1], u[3]);
    plswap(u[4], u[6]); plswap(u[5], u[7]);
#pragma unroll
    for (int q2 = 0; q2 < 2; ++q2) {
      uintx4 pw;
      pw[0] = u[4 * q2 + 0]; pw[1] = u[4 * q2 + 1];
      pw[2] = u[4 * q2 + 2]; pw[3] = u[4 * q2 + 3];
      const ushortx8 pav = __builtin_bit_cast(ushortx8, pw);
      oA = mfma32(*(const ushortx8*)(vb + koff[kc0 + q2]), pav, oA);
      oB = mfma32(*(const ushortx8*)(vb + 4096 + koff[kc0 + q2]), pav, oB);
    }
  };

  int curb = 0;
  for (int t = t0; t < t1; ++t) {
    const int nxt = curb ^ 1;
    if (t + 1 < t1) {
      ksA += kadv; ksB += kadv; vsA += 64; vsB += 64;
      gload_lds16(ksA, &KV[nxt][0][w * 512]);
      gload_lds16(ksB, &KV[nxt][0][2048 + w * 512]);
      gload_lds16(vsA, &KV[nxt][1][w * 512]);
      gload_lds16(vsB, &KV[nxt][1][2048 + w * 512]);
      asm volatile("s_waitcnt vmcnt(4)" ::: "memory");  // tile t (+Q) landed
    } else {
      asm volatile("s_waitcnt vmcnt(0)" ::: "memory");
    }
    __builtin_amdgcn_s_barrier();
    asm volatile("" ::: "memory");

    if (t <= tmax) {
      const bool diag = lastc && (t == tmax);
      const bool halfB = diag && ((w & 1) == 0);  // upper 32 keys fully masked
      const char* kb = (const char*)&KV[curb][0][0];
      const char* vb = (const char*)&KV[curb][1][0];

      // --- A-half: keys key0..key0+31 ---
      {
        f32x16 sA = {};
#pragma unroll
        for (int kc = 0; kc < 4; ++kc)
          sA = mfma32(*(const ushortx8*)(kb + koff[kc]), qf[kc], sA);
        half_pass(sA, vb, 0, diag && halfB);
      }
      // --- B-half: keys key0+32..key0+63 (skipped when fully masked) ---
      if (!halfB) {
        f32x16 sB = {};
#pragma unroll
        for (int kc = 0; kc < 4; ++kc)
          sB = mfma32(*(const ushortx8*)(kb + 4096 + koff[kc]), qf[kc], sB);
        half_pass(sB, vb, 2, diag);
      }
    }

    __builtin_amdgcn_s_barrier();   // all reads of buf curb done before overwrite
    asm volatile("" ::: "memory");
    curb ^= 1;
  }

  // ---- epilogue ----
  if (k == 1) {
    const float inv_l = 1.0f / l_r;
    ushort_t* op = O + ((size_t)(b * NT + qg)) * 1024 + head * 64;
#pragma unroll
    for (int db = 0; db < 2; ++db)
#pragma unroll
      for (int g = 0; g < 4; ++g) {
        ushort4 pk;
        pk.x = bf16_rne((db ? oB[4 * g + 0] : oA[4 * g + 0]) * inv_l);
        pk.y = bf16_rne((db ? oB[4 * g + 1] : oA[4 * g + 1]) * inv_l);
        pk.z = bf16_rne((db ? oB[4 * g + 2] : oA[4 * g + 2]) * inv_l);
        pk.w = bf16_rne((db ? oB[4 * g + 3] : oA[4 * g + 3]) * inv_l);
        *(ushort4*)(op + db * 32 + 8 * g + 4 * h) = pk;
      }
  } else {
    const int s = bh * 32 + c;
    char* wb = (char*)slot_ptr(wsb, dout, s) + w * WAVE_BYTES;
#pragma unroll
    for (int g = 0; g < 4; ++g) {
      ushortx8 pk;
#pragma unroll
      for (int e2 = 0; e2 < 8; ++e2)
        pk[e2] = bf16_rne(g < 2 ? oA[g * 8 + e2] : oB[(g - 2) * 8 + e2]);
      *(ushortx8*)(wb + lane * 64 + g * 16) = pk;
    }
    *(float*)(wb + 4096 + lane * 4) = m_r;
    *(float*)(wb + 4352 + lane * 4) = l_r;
  }
}

// ---------- merge partials for qb >= 5 (max-weighted; k = 2 or 3) ----------
__global__ __launch_bounds__(256)
void attn_merge(const char* __restrict__ wsb, const char* __restrict__ dout,
                ushort_t* __restrict__ O) {
  const int x = blockIdx.x;   // 352 = 32 bh * 11 qb
  const int bh = x & 31;
  const int qi = x >> 5;      // 0..10 -> qb 5..15
  const int qb = 5 + qi;
  const int k = (qb <= 10) ? 2 : 3;
  const int tid = threadIdx.x;
  const int lane = tid & 63;
  const int w = tid >> 6;
  const int l31 = lane & 31;
  const int h = lane >> 5;

  // pass 1: global max over chunks
  float M = -INFINITY;
  for (int jj = 0; jj < k; ++jj) {
    const int s = bh * 32 + MC_TAB[qi][jj];
    const char* wb = slot_ptr(wsb, dout, s) + w * WAVE_BYTES;
    M = fmaxf(M, *(const float*)(wb + 4096 + lane * 4));
  }
  // pass 2: weighted accumulate (slots are L2-hot)
  float o[32];
#pragma unroll
  for (int r = 0; r < 32; ++r) o[r] = 0.f;
  float lacc = 0.f;
  for (int jj = 0; jj < k; ++jj) {
    const int s = bh * 32 + MC_TAB[qi][jj];
    const char* wb = slot_ptr(wsb, dout, s) + w * WAVE_BYTES;
    const float a = exp2f(*(const float*)(wb + 4096 + lane * 4) - M);
    lacc += a * *(const float*)(wb + 4352 + lane * 4);
#pragma unroll
    for (int g = 0; g < 4; ++g) {
      const ushortx8 v = *(const ushortx8*)(wb + lane * 64 + g * 16);
#pragma unroll
      for (int e = 0; e < 8; ++e) o[g * 8 + e] += a * bf2f(v[e]);
    }
  }
  const float inv_l = 1.0f / lacc;
  const int b = bh >> 4, head = bh & 15;
  const int qg = qb * 128 + w * 32 + l31;
  ushort_t* op = O + ((size_t)(b * NT + qg)) * 1024 + head * 64;
#pragma unroll
  for (int db = 0; db < 2; ++db)
#pragma unroll
    for (int g = 0; g < 4; ++g) {
      ushort4 pk;
      pk.x = bf16_rne(o[db * 16 + 4 * g + 0] * inv_l);
      pk.y = bf16_rne(o[db * 16 + 4 * g + 1] * inv_l);
      pk.z = bf16_rne(o[db * 16 + 4 * g + 2] * inv_l);
      pk.w = bf16_rne(o[db * 16 + 4 * g + 3] * inv_l);
      *(ushort4*)(op + db * 32 + 8 * g + 4 * h) = pk;
    }
}

// ---------- launch ----------

extern "C" void kernel_launch(void* const* d_in, const int* in_sizes, int n_in,
                              void* d_out, int out_size, void* d_ws, size_t ws_size,
                              hipStream_t stream) {
  (void)in_sizes; (void)n_in; (void)out_size; (void)ws_size;
  const float* x  = (const float*)d_in[0];
  const float* Wq = (const float*)d_in[1];
  const float* Wk = (const float*)d_in[2];
  const float* Wv = (const float*)d_in[3];
  const float* Wo = (const float*)d_in[4];

  char* ws = (char*)d_ws;
  ushort_t* Xbf    = (ushort_t*)(ws);                        // 4096x1024 bf16 (8 MB)
  ushort_t* Wqkv_t = (ushort_t*)(ws + 8388608);              // 3072x1024 bf16 (6 MB)
  ushort_t* Wo_bf  = (ushort_t*)(ws + 14680064);             // 1024x1024 bf16 (2 MB)
  ushort_t* QKV    = (ushort_t*)(ws + 16777216);             // 4096x2048 bf16 (16 MB)
  ushort_t* Vt     = (ushort_t*)(ws + 33554432);             // 2048x2048 bf16 (8 MB)
  ushort_t* Obf    = (ushort_t*)(ws + 41943040);             // 4096x1024 bf16 (8 MB)

  pack_cast2<<<5120, 256, 0, stream>>>((const float4*)x, Xbf, (const float4*)Wo, Wo_bf);
  pack_wqkv<<<dim3(16, 48), 256, 0, stream>>>(Wq, Wk, Wv, Wqkv_t);

  gemm_bt<1><<<dim3(24, 32), 256, 0, stream>>>(Xbf, Wqkv_t, QKV, Vt, BT, N3, CD);
  attn_fwd11<<<1024, 256, 0, stream>>>(QKV, Vt, Obf, ws, (char*)d_out);
  attn_merge<<<352, 256, 0, stream>>>(ws, (char*)d_out, Obf);
  gemm_bt<0><<<dim3(8, 32), 256, 0, stream>>>(Obf, Wo_bf, d_out, nullptr, BT, CD, CD);
}

// Round 15
// 122.791 us; speedup vs baseline: 1.0869x; 1.0000x over previous
//
#include <hip/hip_runtime.h>

typedef unsigned short ushort_t;
typedef __bf16 bf16x8 __attribute__((ext_vector_type(8)));
typedef float f32x4 __attribute__((ext_vector_type(4)));
typedef float f32x16 __attribute__((ext_vector_type(16)));
typedef unsigned short ushortx8 __attribute__((ext_vector_type(8)));
typedef unsigned int uintx4 __attribute__((ext_vector_type(4)));

#define NH 16
#define HS 64
#define CD 1024
#define NB 2
#define NT 2048
#define BT (NB * NT)   // 4096
#define N3 (3 * CD)    // 3072

#define L2E_DIV32 0.04508422002778011f  // log2(e) / 32  (scale = C^-0.5 = 1/32)

// workspace layout (bytes):
// 0        : Xbf 8MB  |  8388608: Wqkv_t 6MB   <- dead after QKV GEMM -> partial region0
// 14680064 : Wo_bf 2MB (live until last GEMM)
// 16777216 : QKV 16MB  [4096][2048] (Q cols 0-1023 prescaled, K cols 1024-2047)
// 33554432 : Vt 8MB    [2048 rows = b*1024+h*64+d][2048 t]
// 41943040 : Obf 8MB
// partial slots: region0 = ws[0 .. 796*18432 = 14671872) ; overflow -> d_out
// (16MB, dead until the final GEMM rewrites it; merge consumes partials first).
#define QKV_LD 2048
#define SLOT_BYTES 18432      // 4 waves * (64 lanes * 64B O + 256B m + 256B l)
#define WAVE_BYTES 4608
#define R0_SLOTS 796

// ---------- chunk tables: 32 chunks per bh (EXACTLY one round of 1024 blocks),
// ~8.5 tiles each, LPT order (c=0 longest). slot id = bh*32 + c. ----------
__constant__ static const int QB_TAB[32] = {
  10,10,15,15, 4, 9, 9,13,14,14,14,15, 8, 8,12,12,
  13,13, 3, 7, 7,11,11,11,12, 6, 6, 2, 5, 5, 1, 0};
__constant__ static const int T0_TAB[32] = {
   0,11, 0,11, 0, 0,10, 0, 0,10,20,22, 0, 9, 0, 9,
  10,19, 0, 0, 8, 0, 8,16,18, 0, 7, 0, 0, 6, 0, 0};
__constant__ static const int T1_TAB[32] = {
  11,22,11,22,10,10,20,10,10,20,30,32, 9,18, 9,18,
  19,28, 8, 8,16, 8,16,24,26, 7,14, 6, 6,12, 4, 2};
__constant__ static const int K_TAB[32] = {
   2, 2, 3, 3, 1, 2, 2, 3, 3, 3, 3, 3, 2, 2, 3, 3,
   3, 3, 1, 2, 2, 3, 3, 3, 3, 2, 2, 1, 2, 2, 1, 1};
// merge: qb 5..15 (qi 0..10) -> chunk ids c of that qb
__constant__ static const int MC_TAB[11][3] = {
  {28,29, 0}, {25,26, 0}, {19,20, 0}, {12,13, 0}, { 5, 6, 0}, { 0, 1, 0},
  {21,22,23}, {14,15,24}, { 7,16,17}, { 8, 9,10}, { 2, 3,11}};

// ---------- helpers ----------

__device__ __forceinline__ ushort_t bf16_rne(float f) {
  union { float f; unsigned u; } v; v.f = f;
  unsigned u = v.u;
  unsigned r = (u + 0x7FFFu + ((u >> 16) & 1u)) >> 16;
  return (ushort_t)r;
}

__device__ __forceinline__ float bf2f(ushort_t u) {
  union { unsigned u; float f; } v; v.u = ((unsigned)u) << 16; return v.f;
}

__device__ __forceinline__ void gload_lds16(const ushort_t* g, ushort_t* l) {
  __builtin_amdgcn_global_load_lds(
      (const __attribute__((address_space(1))) unsigned int*)g,
      (__attribute__((address_space(3))) unsigned int*)l, 16, 0, 0);
}

__device__ __forceinline__ f32x4 mfma16(ushortx8 a, ushortx8 b, f32x4 c) {
  return __builtin_amdgcn_mfma_f32_16x16x32_bf16(
      __builtin_bit_cast(bf16x8, a), __builtin_bit_cast(bf16x8, b), c, 0, 0, 0);
}

__device__ __forceinline__ f32x16 mfma32(ushortx8 a, ushortx8 b, f32x16 c) {
  return __builtin_amdgcn_mfma_f32_32x32x16_bf16(
      __builtin_bit_cast(bf16x8, a), __builtin_bit_cast(bf16x8, b), c, 0, 0, 0);
}

__device__ __forceinline__ unsigned cvt_pk_bf16(float lo, float hi) {
  unsigned r;
  asm("v_cvt_pk_bf16_f32 %0, %1, %2" : "=v"(r) : "v"(lo), "v"(hi));
  return r;
}

__device__ __forceinline__ void plswap(unsigned &a, unsigned &b) {
  asm volatile("v_permlane32_swap_b32 %0, %1" : "+v"(a), "+v"(b));
}

__device__ __forceinline__ const char* slot_ptr(const char* wsb, const char* dout, int s) {
  return (s < R0_SLOTS) ? wsb + (size_t)s * SLOT_BYTES
                        : dout + (size_t)(s - R0_SLOTS) * SLOT_BYTES;
}

// ---------- pack kernels ----------

// fused: blocks 0..4095 convert x (1M float4), 4096..5119 convert Wo (256K float4)
__global__ __launch_bounds__(256)
void pack_cast2(const float4* __restrict__ x, ushort_t* __restrict__ xout,
                const float4* __restrict__ wo, ushort_t* __restrict__ woout) {
  const int bid = blockIdx.x;
  const float4* in = (bid < 4096) ? x : wo;
  ushort_t* out = (bid < 4096) ? xout : woout;
  const int i = ((bid < 4096) ? bid : (bid - 4096)) * 256 + threadIdx.x;
  const float4 v = in[i];
  ushort4 r;
  r.x = bf16_rne(v.x); r.y = bf16_rne(v.y);
  r.z = bf16_rne(v.z); r.w = bf16_rne(v.w);
  *(ushort4*)(out + (size_t)i * 4) = r;
}

// Wq/Wk/Wv: [H][C][HS] fp32 -> Wqkv_t bf16 [3072 rows = s*1024+h*64+d][1024 cols = c]
__global__ __launch_bounds__(256)
void pack_wqkv(const float* __restrict__ Wq, const float* __restrict__ Wk,
               const float* __restrict__ Wv, ushort_t* __restrict__ out) {
  __shared__ ushort_t tile[64 * 66];
  const int sh = blockIdx.y;
  const int s = sh >> 4, h = sh & 15;
  const float* W = (s == 0) ? Wq : ((s == 1) ? Wk : Wv);
  const int c0 = blockIdx.x * 64;
  const int t = threadIdx.x;
#pragma unroll
  for (int j = 0; j < 16; ++j) {
    const int idx = t + j * 256;
    const int ci = idx >> 6, d = idx & 63;
    const float v = W[(size_t)(h * 1024 + c0 + ci) * 64 + d];
    tile[d * 66 + ci] = bf16_rne(v);
  }
  __syncthreads();
#pragma unroll
  for (int j = 0; j < 16; ++j) {
    const int idx = t + j * 256;
    const int d = idx >> 6, ci = idx & 63;
    out[(size_t)(s * 1024 + h * 64 + d) * 1024 + c0 + ci] = tile[d * 66 + ci];
  }
}

// ---------- GEMM: C[m][n] = sum_k A[m][k] * Bt[n][k] ----------
// MODE 0: plain f32 output, ldc = N.
// MODE 1: QKV mode: col<1024 -> bf16*L2E_DIV32 to QKVo (ld 2048);
//         col in [1024,2048) -> bf16 to QKVo; col >= 2048 -> transposed to Vt.

template <int MODE>
__global__ __launch_bounds__(256)
void gemm_bt(const ushort_t* __restrict__ A, const ushort_t* __restrict__ Bt,
             void* __restrict__ Cv, ushort_t* __restrict__ Vt,
             int M, int N, int K) {
  __shared__ __align__(16) ushort_t ldsA[2][128 * 32];
  __shared__ __align__(16) ushort_t ldsB[2][128 * 32];
  const int tid = threadIdx.x;
  const int lane = tid & 63;
  const int wave = tid >> 6;
  const int row0 = blockIdx.y * 128;
  const int col0 = blockIdx.x * 128;
  const int wm = wave >> 1, wn = wave & 1;

  f32x4 acc[4][4] = {};

  const int ce = (tid & 3) * 8;

  auto stage = [&](int buf, int kt) {
    const int kbase = kt * 32;
#pragma unroll
    for (int j = 0; j < 2; ++j) {
      const int r = j * 64 + (tid >> 2);
      gload_lds16(A + (size_t)(row0 + r) * K + kbase + ce,
                  &ldsA[buf][(j * 256 + wave * 64) * 8]);
      gload_lds16(Bt + (size_t)(col0 + r) * K + kbase + ce,
                  &ldsB[buf][(j * 256 + wave * 64) * 8]);
    }
  };

  const int arow_off = (wm * 64 + (lane & 15)) * 32 + (lane >> 4) * 8;
  const int brow_off = (wn * 64 + (lane & 15)) * 32 + (lane >> 4) * 8;

  auto compute = [&](int buf) {
    ushortx8 af[4], bfr[4];
#pragma unroll
    for (int m = 0; m < 4; ++m)
      af[m] = *(const ushortx8*)&ldsA[buf][arow_off + m * 512];
#pragma unroll
    for (int n = 0; n < 4; ++n)
      bfr[n] = *(const ushortx8*)&ldsB[buf][brow_off + n * 512];
#pragma unroll
    for (int m = 0; m < 4; ++m)
#pragma unroll
      for (int n = 0; n < 4; ++n)
        acc[m][n] = mfma16(af[m], bfr[n], acc[m][n]);
  };

  stage(0, 0);
  __syncthreads();
  const int nk = K >> 5;
  for (int kt = 0; kt < nk; ++kt) {
    const int cur = kt & 1;
    if (kt + 1 < nk) stage(cur ^ 1, kt + 1);
    compute(cur);
    __syncthreads();
  }

#pragma unroll
  for (int m = 0; m < 4; ++m) {
    const int rbase = row0 + wm * 64 + m * 16 + (lane >> 4) * 4;
#pragma unroll
    for (int n = 0; n < 4; ++n) {
      const int col = col0 + wn * 64 + n * 16 + (lane & 15);
      if constexpr (MODE == 0) {
#pragma unroll
        for (int i = 0; i < 4; ++i)
          ((float*)Cv)[(size_t)(rbase + i) * N + col] = acc[m][n][i];
      } else {
        if (col < 2048) {
          const float sc = (col < 1024) ? L2E_DIV32 : 1.0f;
#pragma unroll
          for (int i = 0; i < 4; ++i)
            ((ushort_t*)Cv)[(size_t)(rbase + i) * QKV_LD + col] =
                bf16_rne(acc[m][n][i] * sc);
        } else {
          // V: write transposed. Vt row = b*1024 + (col-2048), col = t
          const int dcol = col - 2048;
          const int bI = rbase >> 11;
          const int t0i = rbase & 2047;
          ushort4 pk;
          pk.x = bf16_rne(acc[m][n][0]);
          pk.y = bf16_rne(acc[m][n][1]);
          pk.z = bf16_rne(acc[m][n][2]);
          pk.w = bf16_rne(acc[m][n][3]);
          *(ushort4*)(Vt + (size_t)(bI * 1024 + dcol) * NT + t0i) = pk;
        }
      }
    }
  }
}

// ---------- causal flash attention v11 ----------
// = R9 kernel body verbatim (split-half softmax, 2-buffer / 2-barrier, counted
//   vmcnt), with EXACTLY-ONE-ROUND chunking: 32 chunks/bh -> 1024 blocks
//   (= 4/CU capacity), ~8.5 tiles each, LPT order. NO persistence, NO atomics.

__global__ __launch_bounds__(256, 4)
void attn_fwd11(const ushort_t* __restrict__ QKV, const ushort_t* __restrict__ Vt,
                ushort_t* __restrict__ O, char* __restrict__ wsb,
                char* __restrict__ dout) {
  __shared__ __align__(16) ushort_t KV[2][2][4096];   // [buf][K/V][64 rows x 64]

  const int tid = threadIdx.x;
  const int lane = tid & 63;
  const int w = tid >> 6;
  const int l31 = lane & 31;
  const int h = lane >> 5;

  // block decode via tables; bh in low 5 bits (XCD spread), longest chunks first
  const int x = blockIdx.x;            // 0..1023
  const int bh = x & 31;
  const int c = x >> 5;                // 0..31, c=0 longest (LPT)
  const int qb = QB_TAB[c];
  const int k  = K_TAB[c];
  const int t0 = T0_TAB[c];
  const int t1 = T1_TAB[c];
  const int nt = 2 * qb + 2;
  const bool lastc = (t1 == nt);

  const int b = bh >> 4, head = bh & 15;
  const size_t base = (size_t)b * NT * QKV_LD;
  const int qg = qb * 128 + w * 32 + l31;
  const int tmax = lastc ? (2 * qb + (w >> 1)) : (t1 - 1);

  // ---- loop-invariant LDS byte offsets (shared by K-frag and V-frag reads) ----
  int koff[4];
#pragma unroll
  for (int kc = 0; kc < 4; ++kc)
    koff[kc] = l31 * 128 + (((2 * kc + h) ^ (l31 & 7)) * 16);

  // ---- staging source pointers at tile t0 ----
  const int rowA = tid >> 3, ccA = tid & 7;
  const int rowB = 32 + rowA;
  const ushort_t* kg = QKV + base + 1024 + head * 64;
  const ushort_t* vg = Vt + (size_t)(bh * 64) * NT;
  const ushort_t* ksA = kg + (size_t)(t0 * 64 + rowA) * QKV_LD + ((ccA ^ (rowA & 7)) * 8);
  const ushort_t* ksB = kg + (size_t)(t0 * 64 + rowB) * QKV_LD + ((ccA ^ (rowB & 7)) * 8);
  const ushort_t* vsA = vg + (size_t)rowA * NT + t0 * 64 + ((ccA ^ (rowA & 7)) * 8);
  const ushort_t* vsB = vg + (size_t)rowB * NT + t0 * 64 + ((ccA ^ (rowB & 7)) * 8);
  const size_t kadv = (size_t)64 * QKV_LD;

  // ---- prologue: stage tile t0 into buffer 0 FIRST, then Q loads ----
  gload_lds16(ksA, &KV[0][0][w * 512]);
  gload_lds16(ksB, &KV[0][0][2048 + w * 512]);
  gload_lds16(vsA, &KV[0][1][w * 512]);
  gload_lds16(vsB, &KV[0][1][2048 + w * 512]);

  ushortx8 qf[4];
  {
    const ushort_t* qp = QKV + base + (size_t)qg * QKV_LD + head * 64 + h * 8;
#pragma unroll
    for (int kc = 0; kc < 4; ++kc) qf[kc] = *(const ushortx8*)(qp + kc * 16);
  }

  f32x16 oA = {}, oB = {};
  float m_r = -INFINITY, l_r = 0.f;

  // one 32-key half: mask -> max -> defer-rescale -> exp2/pack -> PV(kc0,kc0+1)
  auto half_pass = [&](f32x16 s, const char* vb, const int kc0, const bool msk) {
    if (msk) {
#pragma unroll
      for (int r = 0; r < 16; ++r) {
        const int krow = (r & 3) + 8 * (r >> 2) + 4 * h;
        if (krow > l31) s[r] = -INFINITY;
      }
    }
    float mm[8];
#pragma unroll
    for (int r = 0; r < 8; ++r) mm[r] = fmaxf(s[r], s[r + 8]);
#pragma unroll
    for (int st = 4; st >= 1; st >>= 1)
#pragma unroll
      for (int r = 0; r < st; ++r) mm[r] = fmaxf(mm[r], mm[r + st]);
    const float mx = fmaxf(mm[0], __shfl_xor(mm[0], 32, 64));
    if (__any(mx > m_r + 8.0f)) {
      const float mn = fmaxf(m_r, mx);
      const float al = exp2f(m_r - mn);
      m_r = mn; l_r *= al;
#pragma unroll
      for (int r = 0; r < 16; ++r) { oA[r] *= al; oB[r] *= al; }
    }
    unsigned u[8];
    float ps[4];
#pragma unroll
    for (int jj = 0; jj < 4; ++jj) ps[jj] = 0.f;
#pragma unroll
    for (int jj = 0; jj < 8; ++jj) {
      const float e0 = exp2f(s[2 * jj] - m_r);
      const float e1 = exp2f(s[2 * jj + 1] - m_r);
      u[jj] = cvt_pk_bf16(e0, e1);
      ps[jj & 3] += e0 + e1;
    }
    ps[0] += ps[2]; ps[1] += ps[3]; ps[0] += ps[1];
    l_r += ps[0] + __shfl_xor(ps[0], 32, 64);
    plswap(u[0], u[2]); plswap(u[1], u[3]);
    plswap(u[4], u[6]); plswap(u[5], u[7]);
#pragma unroll
    for (int q2 = 0; q2 < 2; ++q2) {
      uintx4 pw;
      pw[0] = u[4 * q2 + 0]; pw[1] = u[4 * q2 + 1];
      pw[2] = u[4 * q2 + 2]; pw[3] = u[4 * q2 + 3];
      const ushortx8 pav = __builtin_bit_cast(ushortx8, pw);
      oA = mfma32(*(const ushortx8*)(vb + koff[kc0 + q2]), pav, oA);
      oB = mfma32(*(const ushortx8*)(vb + 4096 + koff[kc0 + q2]), pav, oB);
    }
  };

  int curb = 0;
  for (int t = t0; t < t1; ++t) {
    const int nxt = curb ^ 1;
    if (t + 1 < t1) {
      ksA += kadv; ksB += kadv; vsA += 64; vsB += 64;
      gload_lds16(ksA, &KV[nxt][0][w * 512]);
      gload_lds16(ksB, &KV[nxt][0][2048 + w * 512]);
      gload_lds16(vsA, &KV[nxt][1][w * 512]);
      gload_lds16(vsB, &KV[nxt][1][2048 + w * 512]);
      asm volatile("s_waitcnt vmcnt(4)" ::: "memory");  // tile t (+Q) landed
    } else {
      asm volatile("s_waitcnt vmcnt(0)" ::: "memory");
    }
    __builtin_amdgcn_s_barrier();
    asm volatile("" ::: "memory");

    if (t <= tmax) {
      const bool diag = lastc && (t == tmax);
      const bool halfB = diag && ((w & 1) == 0);  // upper 32 keys fully masked
      const char* kb = (const char*)&KV[curb][0][0];
      const char* vb = (const char*)&KV[curb][1][0];

      // --- A-half: keys key0..key0+31 ---
      {
        f32x16 sA = {};
#pragma unroll
        for (int kc = 0; kc < 4; ++kc)
          sA = mfma32(*(const ushortx8*)(kb + koff[kc]), qf[kc], sA);
        half_pass(sA, vb, 0, diag && halfB);
      }
      // --- B-half: keys key0+32..key0+63 (skipped when fully masked) ---
      if (!halfB) {
        f32x16 sB = {};
#pragma unroll
        for (int kc = 0; kc < 4; ++kc)
          sB = mfma32(*(const ushortx8*)(kb + 4096 + koff[kc]), qf[kc], sB);
        half_pass(sB, vb, 2, diag);
      }
    }

    __builtin_amdgcn_s_barrier();   // all reads of buf curb done before overwrite
    asm volatile("" ::: "memory");
    curb ^= 1;
  }

  // ---- epilogue ----
  if (k == 1) {
    const float inv_l = 1.0f / l_r;
    ushort_t* op = O + ((size_t)(b * NT + qg)) * 1024 + head * 64;
#pragma unroll
    for (int db = 0; db < 2; ++db)
#pragma unroll
      for (int g = 0; g < 4; ++g) {
        ushort4 pk;
        pk.x = bf16_rne((db ? oB[4 * g + 0] : oA[4 * g + 0]) * inv_l);
        pk.y = bf16_rne((db ? oB[4 * g + 1] : oA[4 * g + 1]) * inv_l);
        pk.z = bf16_rne((db ? oB[4 * g + 2] : oA[4 * g + 2]) * inv_l);
        pk.w = bf16_rne((db ? oB[4 * g + 3] : oA[4 * g + 3]) * inv_l);
        *(ushort4*)(op + db * 32 + 8 * g + 4 * h) = pk;
      }
  } else {
    const int s = bh * 32 + c;
    char* wb = (char*)slot_ptr(wsb, dout, s) + w * WAVE_BYTES;
#pragma unroll
    for (int g = 0; g < 4; ++g) {
      ushortx8 pk;
#pragma unroll
      for (int e2 = 0; e2 < 8; ++e2)
        pk[e2] = bf16_rne(g < 2 ? oA[g * 8 + e2] : oB[(g - 2) * 8 + e2]);
      *(ushortx8*)(wb + lane * 64 + g * 16) = pk;
    }
    *(float*)(wb + 4096 + lane * 4) = m_r;
    *(float*)(wb + 4352 + lane * 4) = l_r;
  }
}

// ---------- merge partials for qb >= 5 (max-weighted; k = 2 or 3) ----------
__global__ __launch_bounds__(256)
void attn_merge(const char* __restrict__ wsb, const char* __restrict__ dout,
                ushort_t* __restrict__ O) {
  const int x = blockIdx.x;   // 352 = 32 bh * 11 qb
  const int bh = x & 31;
  const int qi = x >> 5;      // 0..10 -> qb 5..15
  const int qb = 5 + qi;
  const int k = (qb <= 10) ? 2 : 3;
  const int tid = threadIdx.x;
  const int lane = tid & 63;
  const int w = tid >> 6;
  const int l31 = lane & 31;
  const int h = lane >> 5;

  // pass 1: global max over chunks
  float M = -INFINITY;
  for (int jj = 0; jj < k; ++jj) {
    const int s = bh * 32 + MC_TAB[qi][jj];
    const char* wb = slot_ptr(wsb, dout, s) + w * WAVE_BYTES;
    M = fmaxf(M, *(const float*)(wb + 4096 + lane * 4));
  }
  // pass 2: weighted accumulate (slots are L2-hot)
  float o[32];
#pragma unroll
  for (int r = 0; r < 32; ++r) o[r] = 0.f;
  float lacc = 0.f;
  for (int jj = 0; jj < k; ++jj) {
    const int s = bh * 32 + MC_TAB[qi][jj];
    const char* wb = slot_ptr(wsb, dout, s) + w * WAVE_BYTES;
    const float a = exp2f(*(const float*)(wb + 4096 + lane * 4) - M);
    lacc += a * *(const float*)(wb + 4352 + lane * 4);
#pragma unroll
    for (int g = 0; g < 4; ++g) {
      const ushortx8 v = *(const ushortx8*)(wb + lane * 64 + g * 16);
#pragma unroll
      for (int e = 0; e < 8; ++e) o[g * 8 + e] += a * bf2f(v[e]);
    }
  }
  const float inv_l = 1.0f / lacc;
  const int b = bh >> 4, head = bh & 15;
  const int qg = qb * 128 + w * 32 + l31;
  ushort_t* op = O + ((size_t)(b * NT + qg)) * 1024 + head * 64;
#pragma unroll
  for (int db = 0; db < 2; ++db)
#pragma unroll
    for (int g = 0; g < 4; ++g) {
      ushort4 pk;
      pk.x = bf16_rne(o[db * 16 + 4 * g + 0] * inv_l);
      pk.y = bf16_rne(o[db * 16 + 4 * g + 1] * inv_l);
      pk.z = bf16_rne(o[db * 16 + 4 * g + 2] * inv_l);
      pk.w = bf16_rne(o[db * 16 + 4 * g + 3] * inv_l);
      *(ushort4*)(op + db * 32 + 8 * g + 4 * h) = pk;
    }
}

// ---------- launch ----------

extern "C" void kernel_launch(void* const* d_in, const int* in_sizes, int n_in,
                              void* d_out, int out_size, void* d_ws, size_t ws_size,
                              hipStream_t stream) {
  (void)in_sizes; (void)n_in; (void)out_size; (void)ws_size;
  const float* x  = (const float*)d_in[0];
  const float* Wq = (const float*)d_in[1];
  const float* Wk = (const float*)d_in[2];
  const float* Wv = (const float*)d_in[3];
  const float* Wo = (const float*)d_in[4];

  char* ws = (char*)d_ws;
  ushort_t* Xbf    = (ushort_t*)(ws);                        // 4096x1024 bf16 (8 MB)
  ushort_t* Wqkv_t = (ushort_t*)(ws + 8388608);              // 3072x1024 bf16 (6 MB)
  ushort_t* Wo_bf  = (ushort_t*)(ws + 14680064);             // 1024x1024 bf16 (2 MB)
  ushort_t* QKV    = (ushort_t*)(ws + 16777216);             // 4096x2048 bf16 (16 MB)
  ushort_t* Vt     = (ushort_t*)(ws + 33554432);             // 2048x2048 bf16 (8 MB)
  ushort_t* Obf    = (ushort_t*)(ws + 41943040);             // 4096x1024 bf16 (8 MB)

  pack_cast2<<<5120, 256, 0, stream>>>((const float4*)x, Xbf, (const float4*)Wo, Wo_bf);
  pack_wqkv<<<dim3(16, 48), 256, 0, stream>>>(Wq, Wk, Wv, Wqkv_t);

  gemm_bt<1><<<dim3(24, 32), 256, 0, stream>>>(Xbf, Wqkv_t, QKV, Vt, BT, N3, CD);
  attn_fwd11<<<1024, 256, 0, stream>>>(QKV, Vt, Obf, ws, (char*)d_out);
  attn_merge<<<352, 256, 0, stream>>>(ws, (char*)d_out, Obf);
  gemm_bt<0><<<dim3(8, 32), 256, 0, stream>>>(Obf, Wo_bf, d_out, nullptr, BT, CD, CD);
}

// Round 17
// 119.528 us; speedup vs baseline: 1.1166x; 1.0273x over previous
//
#include <hip/hip_runtime.h>

typedef unsigned short ushort_t;
typedef __bf16 bf16x8 __attribute__((ext_vector_type(8)));
typedef float f32x4 __attribute__((ext_vector_type(4)));
typedef float f32x16 __attribute__((ext_vector_type(16)));
typedef unsigned short ushortx8 __attribute__((ext_vector_type(8)));
typedef unsigned int uintx4 __attribute__((ext_vector_type(4)));

#define NH 16
#define HS 64
#define CD 1024
#define NB 2
#define NT 2048
#define BT (NB * NT)   // 4096
#define N3 (3 * CD)    // 3072

#define L2E_DIV32 0.04508422002778011f  // log2(e) / 32  (scale = C^-0.5 = 1/32)

// workspace layout (bytes):
// 0        : Xbf 8MB  |  8388608: Wqkv_t 6MB   <- dead after QKV GEMM -> partial region0
// 14680064 : Wo_bf 2MB (live until last GEMM)
// 16777216 : QKV 16MB  [4096][2048] (Q cols 0-1023 prescaled, K cols 1024-2047)
// 33554432 : Vt 8MB    [2048 rows = b*1024+h*64+d][2048 t]
// 41943040 : Obf 8MB
// partial slots: region0 = ws[0 .. 796*18432 = 14671872) ; overflow -> d_out
// (16MB, dead until the final GEMM rewrites it; merge consumes partials first).
#define QKV_LD 2048
#define SLOT_BYTES 18432      // 4 waves * (64 lanes * 64B O + 256B m + 256B l)
#define WAVE_BYTES 4608
#define R0_SLOTS 796

// ---------- chunk tables: 32 chunks per bh (EXACTLY one round of 1024 blocks),
// ~8.5 tiles each, LPT order (c=0 longest). slot id = bh*32 + c. ----------
__constant__ static const int QB_TAB[32] = {
  10,10,15,15, 4, 9, 9,13,14,14,14,15, 8, 8,12,12,
  13,13, 3, 7, 7,11,11,11,12, 6, 6, 2, 5, 5, 1, 0};
__constant__ static const int T0_TAB[32] = {
   0,11, 0,11, 0, 0,10, 0, 0,10,20,22, 0, 9, 0, 9,
  10,19, 0, 0, 8, 0, 8,16,18, 0, 7, 0, 0, 6, 0, 0};
__constant__ static const int T1_TAB[32] = {
  11,22,11,22,10,10,20,10,10,20,30,32, 9,18, 9,18,
  19,28, 8, 8,16, 8,16,24,26, 7,14, 6, 6,12, 4, 2};
__constant__ static const int K_TAB[32] = {
   2, 2, 3, 3, 1, 2, 2, 3, 3, 3, 3, 3, 2, 2, 3, 3,
   3, 3, 1, 2, 2, 3, 3, 3, 3, 2, 2, 1, 2, 2, 1, 1};
// merge: qb 5..15 (qi 0..10) -> chunk ids c of that qb
__constant__ static const int MC_TAB[11][3] = {
  {28,29, 0}, {25,26, 0}, {19,20, 0}, {12,13, 0}, { 5, 6, 0}, { 0, 1, 0},
  {21,22,23}, {14,15,24}, { 7,16,17}, { 8, 9,10}, { 2, 3,11}};

// ---------- helpers ----------

__device__ __forceinline__ ushort_t bf16_rne(float f) {
  union { float f; unsigned u; } v; v.f = f;
  unsigned u = v.u;
  unsigned r = (u + 0x7FFFu + ((u >> 16) & 1u)) >> 16;
  return (ushort_t)r;
}

__device__ __forceinline__ float bf2f(ushort_t u) {
  union { unsigned u; float f; } v; v.u = ((unsigned)u) << 16; return v.f;
}

__device__ __forceinline__ void gload_lds16(const ushort_t* g, ushort_t* l) {
  __builtin_amdgcn_global_load_lds(
      (const __attribute__((address_space(1))) unsigned int*)g,
      (__attribute__((address_space(3))) unsigned int*)l, 16, 0, 0);
}

__device__ __forceinline__ f32x4 mfma16(ushortx8 a, ushortx8 b, f32x4 c) {
  return __builtin_amdgcn_mfma_f32_16x16x32_bf16(
      __builtin_bit_cast(bf16x8, a), __builtin_bit_cast(bf16x8, b), c, 0, 0, 0);
}

__device__ __forceinline__ f32x16 mfma32(ushortx8 a, ushortx8 b, f32x16 c) {
  return __builtin_amdgcn_mfma_f32_32x32x16_bf16(
      __builtin_bit_cast(bf16x8, a), __builtin_bit_cast(bf16x8, b), c, 0, 0, 0);
}

__device__ __forceinline__ unsigned cvt_pk_bf16(float lo, float hi) {
  unsigned r;
  asm("v_cvt_pk_bf16_f32 %0, %1, %2" : "=v"(r) : "v"(lo), "v"(hi));
  return r;
}

__device__ __forceinline__ void plswap(unsigned &a, unsigned &b) {
  asm volatile("v_permlane32_swap_b32 %0, %1" : "+v"(a), "+v"(b));
}

__device__ __forceinline__ const char* slot_ptr(const char* wsb, const char* dout, int s) {
  return (s < R0_SLOTS) ? wsb + (size_t)s * SLOT_BYTES
                        : dout + (size_t)(s - R0_SLOTS) * SLOT_BYTES;
}

// ---------- pack kernels ----------

// fused: blocks 0..4095 convert x (1M float4), 4096..5119 convert Wo (256K float4)
__global__ __launch_bounds__(256)
void pack_cast2(const float4* __restrict__ x, ushort_t* __restrict__ xout,
                const float4* __restrict__ wo, ushort_t* __restrict__ woout) {
  const int bid = blockIdx.x;
  const float4* in = (bid < 4096) ? x : wo;
  ushort_t* out = (bid < 4096) ? xout : woout;
  const int i = ((bid < 4096) ? bid : (bid - 4096)) * 256 + threadIdx.x;
  const float4 v = in[i];
  ushort4 r;
  r.x = bf16_rne(v.x); r.y = bf16_rne(v.y);
  r.z = bf16_rne(v.z); r.w = bf16_rne(v.w);
  *(ushort4*)(out + (size_t)i * 4) = r;
}

// Wq/Wk/Wv: [H][C][HS] fp32 -> Wqkv_t bf16 [3072 rows = s*1024+h*64+d][1024 cols = c]
__global__ __launch_bounds__(256)
void pack_wqkv(const float* __restrict__ Wq, const float* __restrict__ Wk,
               const float* __restrict__ Wv, ushort_t* __restrict__ out) {
  __shared__ ushort_t tile[64 * 66];
  const int sh = blockIdx.y;
  const int s = sh >> 4, h = sh & 15;
  const float* W = (s == 0) ? Wq : ((s == 1) ? Wk : Wv);
  const int c0 = blockIdx.x * 64;
  const int t = threadIdx.x;
#pragma unroll
  for (int j = 0; j < 16; ++j) {
    const int idx = t + j * 256;
    const int ci = idx >> 6, d = idx & 63;
    const float v = W[(size_t)(h * 1024 + c0 + ci) * 64 + d];
    tile[d * 66 + ci] = bf16_rne(v);
  }
  __syncthreads();
#pragma unroll
  for (int j = 0; j < 16; ++j) {
    const int idx = t + j * 256;
    const int d = idx >> 6, ci = idx & 63;
    out[(size_t)(s * 1024 + h * 64 + d) * 1024 + c0 + ci] = tile[d * 66 + ci];
  }
}

// ---------- GEMM (128x128 tile): QKV mode ----------
// col<1024 -> bf16*L2E_DIV32 to QKVo (ld 2048); col in [1024,2048) -> bf16;
// col >= 2048 -> transposed to Vt.

__global__ __launch_bounds__(256)
void gemm_bt_qkv(const ushort_t* __restrict__ A, const ushort_t* __restrict__ Bt,
                 ushort_t* __restrict__ QKVo, ushort_t* __restrict__ Vt, int K) {
  __shared__ __align__(16) ushort_t ldsA[2][128 * 32];
  __shared__ __align__(16) ushort_t ldsB[2][128 * 32];
  const int tid = threadIdx.x;
  const int lane = tid & 63;
  const int wave = tid >> 6;
  const int row0 = blockIdx.y * 128;
  const int col0 = blockIdx.x * 128;
  const int wm = wave >> 1, wn = wave & 1;

  f32x4 acc[4][4] = {};

  const int ce = (tid & 3) * 8;

  auto stage = [&](int buf, int kt) {
    const int kbase = kt * 32;
#pragma unroll
    for (int j = 0; j < 2; ++j) {
      const int r = j * 64 + (tid >> 2);
      gload_lds16(A + (size_t)(row0 + r) * K + kbase + ce,
                  &ldsA[buf][(j * 256 + wave * 64) * 8]);
      gload_lds16(Bt + (size_t)(col0 + r) * K + kbase + ce,
                  &ldsB[buf][(j * 256 + wave * 64) * 8]);
    }
  };

  const int arow_off = (wm * 64 + (lane & 15)) * 32 + (lane >> 4) * 8;
  const int brow_off = (wn * 64 + (lane & 15)) * 32 + (lane >> 4) * 8;

  auto compute = [&](int buf) {
    ushortx8 af[4], bfr[4];
#pragma unroll
    for (int m = 0; m < 4; ++m)
      af[m] = *(const ushortx8*)&ldsA[buf][arow_off + m * 512];
#pragma unroll
    for (int n = 0; n < 4; ++n)
      bfr[n] = *(const ushortx8*)&ldsB[buf][brow_off + n * 512];
#pragma unroll
    for (int m = 0; m < 4; ++m)
#pragma unroll
      for (int n = 0; n < 4; ++n)
        acc[m][n] = mfma16(af[m], bfr[n], acc[m][n]);
  };

  stage(0, 0);
  __syncthreads();
  const int nk = K >> 5;
  for (int kt = 0; kt < nk; ++kt) {
    const int cur = kt & 1;
    if (kt + 1 < nk) stage(cur ^ 1, kt + 1);
    compute(cur);
    __syncthreads();
  }

#pragma unroll
  for (int m = 0; m < 4; ++m) {
    const int rbase = row0 + wm * 64 + m * 16 + (lane >> 4) * 4;
#pragma unroll
    for (int n = 0; n < 4; ++n) {
      const int col = col0 + wn * 64 + n * 16 + (lane & 15);
      if (col < 2048) {
        const float sc = (col < 1024) ? L2E_DIV32 : 1.0f;
#pragma unroll
        for (int i = 0; i < 4; ++i)
          QKVo[(size_t)(rbase + i) * QKV_LD + col] = bf16_rne(acc[m][n][i] * sc);
      } else {
        // V: write transposed. Vt row = b*1024 + (col-2048), col = t
        const int dcol = col - 2048;
        const int bI = rbase >> 11;
        const int t0i = rbase & 2047;
        ushort4 pk;
        pk.x = bf16_rne(acc[m][n][0]);
        pk.y = bf16_rne(acc[m][n][1]);
        pk.z = bf16_rne(acc[m][n][2]);
        pk.w = bf16_rne(acc[m][n][3]);
        *(ushort4*)(Vt + (size_t)(bI * 1024 + dcol) * NT + t0i) = pk;
      }
    }
  }
}

// ---------- GEMM (128x64 tile, f32 out): for the output projection ----------
// grid (N/64, M/128) = 512 blocks -> 2-4 blocks/CU (vs 1 with the 128x128 tile).

__global__ __launch_bounds__(256)
void gemm_bt64(const ushort_t* __restrict__ A, const ushort_t* __restrict__ Bt,
               float* __restrict__ C, int M, int N, int K) {
  __shared__ __align__(16) ushort_t ldsA[2][128 * 32];
  __shared__ __align__(16) ushort_t ldsB[2][64 * 32];
  const int tid = threadIdx.x;
  const int lane = tid & 63;
  const int wave = tid >> 6;
  const int row0 = blockIdx.y * 128;
  const int col0 = blockIdx.x * 64;
  const int wm = wave >> 1, wn = wave & 1;

  f32x4 acc[4][2] = {};

  const int ce = (tid & 3) * 8;

  auto stage = [&](int buf, int kt) {
    const int kbase = kt * 32;
#pragma unroll
    for (int j = 0; j < 2; ++j) {
      const int r = j * 64 + (tid >> 2);
      gload_lds16(A + (size_t)(row0 + r) * K + kbase + ce,
                  &ldsA[buf][(j * 256 + wave * 64) * 8]);
    }
    gload_lds16(Bt + (size_t)(col0 + (tid >> 2)) * K + kbase + ce,
                &ldsB[buf][(wave * 64) * 8]);
  };

  const int arow_off = (wm * 64 + (lane & 15)) * 32 + (lane >> 4) * 8;
  const int brow_off = (wn * 32 + (lane & 15)) * 32 + (lane >> 4) * 8;

  auto compute = [&](int buf) {
    ushortx8 af[4], bfr[2];
#pragma unroll
    for (int m = 0; m < 4; ++m)
      af[m] = *(const ushortx8*)&ldsA[buf][arow_off + m * 512];
#pragma unroll
    for (int n = 0; n < 2; ++n)
      bfr[n] = *(const ushortx8*)&ldsB[buf][brow_off + n * 512];
#pragma unroll
    for (int m = 0; m < 4; ++m)
#pragma unroll
      for (int n = 0; n < 2; ++n)
        acc[m][n] = mfma16(af[m], bfr[n], acc[m][n]);
  };

  stage(0, 0);
  __syncthreads();
  const int nk = K >> 5;
  for (int kt = 0; kt < nk; ++kt) {
    const int cur = kt & 1;
    if (kt + 1 < nk) stage(cur ^ 1, kt + 1);
    compute(cur);
    __syncthreads();
  }

#pragma unroll
  for (int m = 0; m < 4; ++m) {
    const int rbase = row0 + wm * 64 + m * 16 + (lane >> 4) * 4;
#pragma unroll
    for (int n = 0; n < 2; ++n) {
      const int col = col0 + wn * 32 + n * 16 + (lane & 15);
#pragma unroll
      for (int i = 0; i < 4; ++i)
        C[(size_t)(rbase + i) * N + col] = acc[m][n][i];
    }
  }
}

// ---------- causal flash attention v13 ----------
// = R15 kernel (split-half softmax, 2-buffer / 2-barrier, counted vmcnt,
//   one-round chunking, __shfl_xor cross-half reductions) + s_setprio around
//   MFMA clusters (T5) + max3-friendly fmax tree (T17).

__global__ __launch_bounds__(256, 4)
void attn_fwd13(const ushort_t* __restrict__ QKV, const ushort_t* __restrict__ Vt,
                ushort_t* __restrict__ O, char* __restrict__ wsb,
                char* __restrict__ dout) {
  __shared__ __align__(16) ushort_t KV[2][2][4096];   // [buf][K/V][64 rows x 64]

  const int tid = threadIdx.x;
  const int lane = tid & 63;
  const int w = tid >> 6;
  const int l31 = lane & 31;
  const int h = lane >> 5;

  // block decode via tables; bh in low 5 bits (XCD spread), longest chunks first
  const int x = blockIdx.x;            // 0..1023
  const int bh = x & 31;
  const int c = x >> 5;                // 0..31, c=0 longest (LPT)
  const int qb = QB_TAB[c];
  const int k  = K_TAB[c];
  const int t0 = T0_TAB[c];
  const int t1 = T1_TAB[c];
  const int nt = 2 * qb + 2;
  const bool lastc = (t1 == nt);

  const int b = bh >> 4, head = bh & 15;
  const size_t base = (size_t)b * NT * QKV_LD;
  const int qg = qb * 128 + w * 32 + l31;
  const int tmax = lastc ? (2 * qb + (w >> 1)) : (t1 - 1);

  // ---- loop-invariant LDS byte offsets (shared by K-frag and V-frag reads) ----
  int koff[4];
#pragma unroll
  for (int kc = 0; kc < 4; ++kc)
    koff[kc] = l31 * 128 + (((2 * kc + h) ^ (l31 & 7)) * 16);

  // ---- staging source pointers at tile t0 ----
  const int rowA = tid >> 3, ccA = tid & 7;
  const int rowB = 32 + rowA;
  const ushort_t* kg = QKV + base + 1024 + head * 64;
  const ushort_t* vg = Vt + (size_t)(bh * 64) * NT;
  const ushort_t* ksA = kg + (size_t)(t0 * 64 + rowA) * QKV_LD + ((ccA ^ (rowA & 7)) * 8);
  const ushort_t* ksB = kg + (size_t)(t0 * 64 + rowB) * QKV_LD + ((ccA ^ (rowB & 7)) * 8);
  const ushort_t* vsA = vg + (size_t)rowA * NT + t0 * 64 + ((ccA ^ (rowA & 7)) * 8);
  const ushort_t* vsB = vg + (size_t)rowB * NT + t0 * 64 + ((ccA ^ (rowB & 7)) * 8);
  const size_t kadv = (size_t)64 * QKV_LD;

  // ---- prologue: stage tile t0 into buffer 0 FIRST, then Q loads ----
  gload_lds16(ksA, &KV[0][0][w * 512]);
  gload_lds16(ksB, &KV[0][0][2048 + w * 512]);
  gload_lds16(vsA, &KV[0][1][w * 512]);
  gload_lds16(vsB, &KV[0][1][2048 + w * 512]);

  ushortx8 qf[4];
  {
    const ushort_t* qp = QKV + base + (size_t)qg * QKV_LD + head * 64 + h * 8;
#pragma unroll
    for (int kc = 0; kc < 4; ++kc) qf[kc] = *(const ushortx8*)(qp + kc * 16);
  }

  f32x16 oA = {}, oB = {};
  float m_r = -INFINITY, l_r = 0.f;

  // one 32-key half: mask -> max -> defer-rescale -> exp2/pack -> PV(kc0,kc0+1)
  auto half_pass = [&](f32x16 s, const char* vb, const int kc0, const bool msk) {
    if (msk) {
#pragma unroll
      for (int r = 0; r < 16; ++r) {
        const int krow = (r & 3) + 8 * (r >> 2) + 4 * h;
        if (krow > l31) s[r] = -INFINITY;
      }
    }
    // max tree in triples (v_max3 fusion)
    const float t0m = fmaxf(fmaxf(s[0], s[1]), s[2]);
    const float t1m = fmaxf(fmaxf(s[3], s[4]), s[5]);
    const float t2m = fmaxf(fmaxf(s[6], s[7]), s[8]);
    const float t3m = fmaxf(fmaxf(s[9], s[10]), s[11]);
    const float t4m = fmaxf(fmaxf(s[12], s[13]), s[14]);
    const float u0m = fmaxf(fmaxf(t0m, t1m), t2m);
    const float u1m = fmaxf(fmaxf(t3m, t4m), s[15]);
    float mx = fmaxf(u0m, u1m);
    mx = fmaxf(mx, __shfl_xor(mx, 32, 64));
    if (__any(mx > m_r + 8.0f)) {
      const float mn = fmaxf(m_r, mx);
      const float al = exp2f(m_r - mn);
      m_r = mn; l_r *= al;
#pragma unroll
      for (int r = 0; r < 16; ++r) { oA[r] *= al; oB[r] *= al; }
    }
    unsigned u[8];
    float ps[4];
#pragma unroll
    for (int jj = 0; jj < 4; ++jj) ps[jj] = 0.f;
#pragma unroll
    for (int jj = 0; jj < 8; ++jj) {
      const float e0 = exp2f(s[2 * jj] - m_r);
      const float e1 = exp2f(s[2 * jj + 1] - m_r);
      u[jj] = cvt_pk_bf16(e0, e1);
      ps[jj & 3] += e0 + e1;
    }
    ps[0] += ps[2]; ps[1] += ps[3]; ps[0] += ps[1];
    l_r += ps[0] + __shfl_xor(ps[0], 32, 64);
    plswap(u[0], u[2]); plswap(u[1], u[3]);
    plswap(u[4], u[6]); plswap(u[5], u[7]);
    __builtin_amdgcn_s_setprio(1);
#pragma unroll
    for (int q2 = 0; q2 < 2; ++q2) {
      uintx4 pw;
      pw[0] = u[4 * q2 + 0]; pw[1] = u[4 * q2 + 1];
      pw[2] = u[4 * q2 + 2]; pw[3] = u[4 * q2 + 3];
      const ushortx8 pav = __builtin_bit_cast(ushortx8, pw);
      oA = mfma32(*(const ushortx8*)(vb + koff[kc0 + q2]), pav, oA);
      oB = mfma32(*(const ushortx8*)(vb + 4096 + koff[kc0 + q2]), pav, oB);
    }
    __builtin_amdgcn_s_setprio(0);
  };

  int curb = 0;
  for (int t = t0; t < t1; ++t) {
    const int nxt = curb ^ 1;
    if (t + 1 < t1) {
      ksA += kadv; ksB += kadv; vsA += 64; vsB += 64;
      gload_lds16(ksA, &KV[nxt][0][w * 512]);
      gload_lds16(ksB, &KV[nxt][0][2048 + w * 512]);
      gload_lds16(vsA, &KV[nxt][1][w * 512]);
      gload_lds16(vsB, &KV[nxt][1][2048 + w * 512]);
      asm volatile("s_waitcnt vmcnt(4)" ::: "memory");  // tile t (+Q) landed
    } else {
      asm volatile("s_waitcnt vmcnt(0)" ::: "memory");
    }
    __builtin_amdgcn_s_barrier();
    asm volatile("" ::: "memory");

    if (t <= tmax) {
      const bool diag = lastc && (t == tmax);
      const bool halfB = diag && ((w & 1) == 0);  // upper 32 keys fully masked
      const char* kb = (const char*)&KV[curb][0][0];
      const char* vb = (const char*)&KV[curb][1][0];

      // --- A-half: keys key0..key0+31 ---
      {
        f32x16 sA = {};
        __builtin_amdgcn_s_setprio(1);
#pragma unroll
        for (int kc = 0; kc < 4; ++kc)
          sA = mfma32(*(const ushortx8*)(kb + koff[kc]), qf[kc], sA);
        __builtin_amdgcn_s_setprio(0);
        half_pass(sA, vb, 0, diag && halfB);
      }
      // --- B-half: keys key0+32..key0+63 (skipped when fully masked) ---
      if (!halfB) {
        f32x16 sB = {};
        __builtin_amdgcn_s_setprio(1);
#pragma unroll
        for (int kc = 0; kc < 4; ++kc)
          sB = mfma32(*(const ushortx8*)(kb + 4096 + koff[kc]), qf[kc], sB);
        __builtin_amdgcn_s_setprio(0);
        half_pass(sB, vb, 2, diag);
      }
    }

    __builtin_amdgcn_s_barrier();   // all reads of buf curb done before overwrite
    asm volatile("" ::: "memory");
    curb ^= 1;
  }

  // ---- epilogue ----
  if (k == 1) {
    const float inv_l = 1.0f / l_r;
    ushort_t* op = O + ((size_t)(b * NT + qg)) * 1024 + head * 64;
#pragma unroll
    for (int db = 0; db < 2; ++db)
#pragma unroll
      for (int g = 0; g < 4; ++g) {
        ushort4 pk;
        pk.x = bf16_rne((db ? oB[4 * g + 0] : oA[4 * g + 0]) * inv_l);
        pk.y = bf16_rne((db ? oB[4 * g + 1] : oA[4 * g + 1]) * inv_l);
        pk.z = bf16_rne((db ? oB[4 * g + 2] : oA[4 * g + 2]) * inv_l);
        pk.w = bf16_rne((db ? oB[4 * g + 3] : oA[4 * g + 3]) * inv_l);
        *(ushort4*)(op + db * 32 + 8 * g + 4 * h) = pk;
      }
  } else {
    const int s = bh * 32 + c;
    char* wb = (char*)slot_ptr(wsb, dout, s) + w * WAVE_BYTES;
#pragma unroll
    for (int g = 0; g < 4; ++g) {
      ushortx8 pk;
#pragma unroll
      for (int e2 = 0; e2 < 8; ++e2)
        pk[e2] = bf16_rne(g < 2 ? oA[g * 8 + e2] : oB[(g - 2) * 8 + e2]);
      *(ushortx8*)(wb + lane * 64 + g * 16) = pk;
    }
    *(float*)(wb + 4096 + lane * 4) = m_r;
    *(float*)(wb + 4352 + lane * 4) = l_r;
  }
}

// ---------- merge partials for qb >= 5 (max-weighted; k = 2 or 3) ----------
__global__ __launch_bounds__(256)
void attn_merge(const char* __restrict__ wsb, const char* __restrict__ dout,
                ushort_t* __restrict__ O) {
  const int x = blockIdx.x;   // 352 = 32 bh * 11 qb
  const int bh = x & 31;
  const int qi = x >> 5;      // 0..10 -> qb 5..15
  const int qb = 5 + qi;
  const int k = (qb <= 10) ? 2 : 3;
  const int tid = threadIdx.x;
  const int lane = tid & 63;
  const int w = tid >> 6;
  const int l31 = lane & 31;
  const int h = lane >> 5;

  // pass 1: global max over chunks
  float M = -INFINITY;
  for (int jj = 0; jj < k; ++jj) {
    const int s = bh * 32 + MC_TAB[qi][jj];
    const char* wb = slot_ptr(wsb, dout, s) + w * WAVE_BYTES;
    M = fmaxf(M, *(const float*)(wb + 4096 + lane * 4));
  }
  // pass 2: weighted accumulate (slots are L2-hot)
  float o[32];
#pragma unroll
  for (int r = 0; r < 32; ++r) o[r] = 0.f;
  float lacc = 0.f;
  for (int jj = 0; jj < k; ++jj) {
    const int s = bh * 32 + MC_TAB[qi][jj];
    const char* wb = slot_ptr(wsb, dout, s) + w * WAVE_BYTES;
    const float a = exp2f(*(const float*)(wb + 4096 + lane * 4) - M);
    lacc += a * *(const float*)(wb + 4352 + lane * 4);
#pragma unroll
    for (int g = 0; g < 4; ++g) {
      const ushortx8 v = *(const ushortx8*)(wb + lane * 64 + g * 16);
#pragma unroll
      for (int e = 0; e < 8; ++e) o[g * 8 + e] += a * bf2f(v[e]);
    }
  }
  const float inv_l = 1.0f / lacc;
  const int b = bh >> 4, head = bh & 15;
  const int qg = qb * 128 + w * 32 + l31;
  ushort_t* op = O + ((size_t)(b * NT + qg)) * 1024 + head * 64;
#pragma unroll
  for (int db = 0; db < 2; ++db)
#pragma unroll
    for (int g = 0; g < 4; ++g) {
      ushort4 pk;
      pk.x = bf16_rne(o[db * 16 + 4 * g + 0] * inv_l);
      pk.y = bf16_rne(o[db * 16 + 4 * g + 1] * inv_l);
      pk.z = bf16_rne(o[db * 16 + 4 * g + 2] * inv_l);
      pk.w = bf16_rne(o[db * 16 + 4 * g + 3] * inv_l);
      *(ushort4*)(op + db * 32 + 8 * g + 4 * h) = pk;
    }
}

// ---------- launch ----------

extern "C" void kernel_launch(void* const* d_in, const int* in_sizes, int n_in,
                              void* d_out, int out_size, void* d_ws, size_t ws_size,
                              hipStream_t stream) {
  (void)in_sizes; (void)n_in; (void)out_size; (void)ws_size;
  const float* x  = (const float*)d_in[0];
  const float* Wq = (const float*)d_in[1];
  const float* Wk = (const float*)d_in[2];
  const float* Wv = (const float*)d_in[3];
  const float* Wo = (const float*)d_in[4];

  char* ws = (char*)d_ws;
  ushort_t* Xbf    = (ushort_t*)(ws);                        // 4096x1024 bf16 (8 MB)
  ushort_t* Wqkv_t = (ushort_t*)(ws + 8388608);              // 3072x1024 bf16 (6 MB)
  ushort_t* Wo_bf  = (ushort_t*)(ws + 14680064);             // 1024x1024 bf16 (2 MB)
  ushort_t* QKV    = (ushort_t*)(ws + 16777216);             // 4096x2048 bf16 (16 MB)
  ushort_t* Vt     = (ushort_t*)(ws + 33554432);             // 2048x2048 bf16 (8 MB)
  ushort_t* Obf    = (ushort_t*)(ws + 41943040);             // 4096x1024 bf16 (8 MB)

  pack_cast2<<<5120, 256, 0, stream>>>((const float4*)x, Xbf, (const float4*)Wo, Wo_bf);
  pack_wqkv<<<dim3(16, 48), 256, 0, stream>>>(Wq, Wk, Wv, Wqkv_t);

  gemm_bt_qkv<<<dim3(24, 32), 256, 0, stream>>>(Xbf, Wqkv_t, QKV, Vt, CD);
  attn_fwd13<<<1024, 256, 0, stream>>>(QKV, Vt, Obf, ws, (char*)d_out);
  attn_merge<<<352, 256, 0, stream>>>(ws, (char*)d_out, Obf);
  gemm_bt64<<<dim3(16, 32), 256, 0, stream>>>(Obf, Wo_bf, (float*)d_out, BT, CD, CD);
}